// Round 4
// baseline (1222.019 us; speedup 1.0000x reference)
//
#include <hip/hip_runtime.h>
#include <stdint.h>

typedef unsigned short u16;
using us8   = __attribute__((ext_vector_type(8))) unsigned short;
using us4   = __attribute__((ext_vector_type(4))) unsigned short;
using bf16x8 = __attribute__((ext_vector_type(8))) __bf16;
using f32x4 = __attribute__((ext_vector_type(4))) float;

#define DEV static __device__ __forceinline__

DEV float bf2f(u16 u) { union { uint32_t i; float f; } v; v.i = (uint32_t)u << 16; return v.f; }
DEV u16 f2bf(float f) {
    union { float f; uint32_t i; } v; v.f = f;
    uint32_t u = v.i;
    return (u16)((u + 0x7FFFu + ((u >> 16) & 1u)) >> 16);
}

// ---------------------------------------------------------------------------
// Per-tensor float dtype detection: *flag = 2 (bf16) or 3 (f32).
// ---------------------------------------------------------------------------
__global__ __launch_bounds__(256) void k_detect_f(const void* src, int nwords, int* flag)
{
    __shared__ int cnt[3];
    int t = threadIdx.x;
    if (t < 3) cnt[t] = 0;
    __syncthreads();
    const u16* p = (const u16*)src;
    int nze = 0, pe = 0, nzo = 0;
    for (int i = t; i < nwords; i += 256) {
        u16 w = p[i];
        if (w == 0) continue;
        int e = (w >> 7) & 0xFF;
        bool pl = (e >= 90 && e <= 140);
        if ((i & 1) == 0) { nze++; if (pl) pe++; }
        else nzo++;
    }
    atomicAdd(&cnt[0], nze); atomicAdd(&cnt[1], pe); atomicAdd(&cnt[2], nzo);
    __syncthreads();
    if (t == 0) {
        int f;
        if (cnt[0] > 0)       f = (cnt[1] * 10 >= cnt[0] * 6) ? 2 : 3;
        else if (cnt[2] > 0)  f = 3;
        else                  f = 2;
        *flag = f;
    }
}

// mask dtype: *flag = 0 (i8), 1 (i32), 2 (bf16), 3 (f32); values are 0/1.
__global__ __launch_bounds__(256) void k_detect_mask(const void* mask, int* flag)
{
    __shared__ int cnt[4];
    int t = threadIdx.x;
    if (t < 4) cnt[t] = 0;
    __syncthreads();
    const uint8_t* m = (const uint8_t*)mask;
    int c0 = 0, c1 = 0, c2 = 0, c3 = 0;
    for (int i = t; i < 4096; i += 256) {
        uint8_t b = m[i];
        int mod = i & 3;
        if (b == 0x3F && mod == 1) c0++;
        if (b == 0x3F && mod == 3) c1++;
        if (b == 1 && mod != 0) c2++;
        if (b == 1 && mod == 0) c3++;
    }
    atomicAdd(&cnt[0], c0); atomicAdd(&cnt[1], c1); atomicAdd(&cnt[2], c2); atomicAdd(&cnt[3], c3);
    __syncthreads();
    if (t == 0) {
        int mf;
        if (cnt[0] > 0) mf = 2;
        else if (cnt[1] > 0) mf = 3;
        else if (cnt[2] > 0) mf = 0;
        else if (cnt[3] > 0) mf = 1;
        else mf = 0;
        *flag = mf;
    }
}

__global__ __launch_bounds__(256) void k_expand_mask(const void* mask, const int* flag, float* mb)
{
    int i = blockIdx.x * 256 + threadIdx.x;
    if (i >= 4096) return;
    int f = *flag;
    bool on;
    if (f == 0)      on = ((const uint8_t*)mask)[i]  != 0;
    else if (f == 1) on = ((const int*)mask)[i]      != 0;
    else if (f == 2) on = ((const u16*)mask)[i]      != 0;
    else             on = ((const uint32_t*)mask)[i] != 0;
    mb[i] = on ? -1e9f : 0.0f;
}

__global__ __launch_bounds__(256) void k_convert_bf(const void* src, u16* dst, int n, const int* flag)
{
    int i = blockIdx.x * 256 + threadIdx.x;
    if (i >= n) return;
    if (*flag == 2) dst[i] = ((const u16*)src)[i];
    else            dst[i] = f2bf(((const float*)src)[i]);
}

// dst (C x R) = transpose of src (R x C), bf16 out
__global__ __launch_bounds__(256) void k_transpose_bf(const void* src, u16* dst, int R, int C, const int* flag)
{
    int i = blockIdx.x * 256 + threadIdx.x;
    if (i >= R * C) return;
    int c = i / R, r = i - c * R;
    if (*flag == 2) dst[i] = ((const u16*)src)[(size_t)r * C + c];
    else            dst[i] = f2bf(((const float*)src)[(size_t)r * C + c]);
}

__global__ __launch_bounds__(256) void k_convert_f32(const void* src, float* dst, int n, const int* flag)
{
    int i = blockIdx.x * 256 + threadIdx.x;
    if (i >= n) return;
    if (*flag == 2) dst[i] = bf2f(((const u16*)src)[i]);
    else            dst[i] = ((const float*)src)[i];
}

// ---------------------------------------------------------------------------
// MFMA GEMM core: C(M x N) = A(M x K, row-major, lda) * B(K x N), B given
// TRANSPOSED (Bt: N x K row-major, ldb). BK=32, fp32 accum, LDS rows pad 40.
// ---------------------------------------------------------------------------
template<int BM, int BN, int WR, int WC, int TM, int TN>
DEV void gemm_tile(const u16* __restrict__ A, int lda,
                   const u16* __restrict__ Bt, int ldb, int K,
                   u16* As, u16* Bs, f32x4 (&acc)[TM][TN])
{
    constexpr int NT = WR * WC * 64;
    const int t = threadIdx.x;
    const int lane = t & 63;
    const int wave = t >> 6;
    const int wr = wave / WC;
    const int wc = wave % WC;
    const int m16 = lane & 15;
    const int quad = lane >> 4;

#pragma unroll
    for (int i = 0; i < TM; i++)
#pragma unroll
        for (int j = 0; j < TN; j++) {
            acc[i][j][0] = 0.f; acc[i][j][1] = 0.f; acc[i][j][2] = 0.f; acc[i][j][3] = 0.f;
        }

    for (int kb = 0; kb < K; kb += 32) {
#pragma unroll
        for (int pass = 0; pass < (BM * 4) / NT; pass++) {
            int idx = t + pass * NT;
            int r = idx >> 2, c8 = (idx & 3) << 3;
            *(us8*)(As + r * 40 + c8) = *(const us8*)(A + (size_t)r * lda + kb + c8);
        }
#pragma unroll
        for (int pass = 0; pass < (BN * 4) / NT; pass++) {
            int idx = t + pass * NT;
            int r = idx >> 2, c8 = (idx & 3) << 3;
            *(us8*)(Bs + r * 40 + c8) = *(const us8*)(Bt + (size_t)r * ldb + kb + c8);
        }
        __syncthreads();
        bf16x8 af[TM], bfr[TN];
#pragma unroll
        for (int i = 0; i < TM; i++)
            af[i] = *(const bf16x8*)(As + (wr * TM * 16 + i * 16 + m16) * 40 + quad * 8);
#pragma unroll
        for (int j = 0; j < TN; j++)
            bfr[j] = *(const bf16x8*)(Bs + (wc * TN * 16 + j * 16 + m16) * 40 + quad * 8);
#pragma unroll
        for (int i = 0; i < TM; i++)
#pragma unroll
            for (int j = 0; j < TN; j++)
                acc[i][j] = __builtin_amdgcn_mfma_f32_16x16x32_bf16(af[i], bfr[j], acc[i][j], 0, 0, 0);
        __syncthreads();
    }
}

template<bool RELU>
__global__ __launch_bounds__(256) void k_gemm_std(const u16* __restrict__ A, int lda,
                                                  const u16* __restrict__ Bt, int ldb,
                                                  const float* __restrict__ bias,
                                                  u16* __restrict__ C, int ldc, int K)
{
    __shared__ __align__(16) u16 As[128 * 40];
    __shared__ __align__(16) u16 Bs[128 * 40];
    const u16* Ab = A + (size_t)blockIdx.y * 128 * lda;
    const u16* Bb = Bt + (size_t)blockIdx.x * 128 * ldb;
    f32x4 acc[4][4];
    gemm_tile<128, 128, 2, 2, 4, 4>(Ab, lda, Bb, ldb, K, As, Bs, acc);

    const int t = threadIdx.x, lane = t & 63, wave = t >> 6;
    const int wr = wave >> 1, wc = wave & 1, m16 = lane & 15, quad = lane >> 4;
    const size_t rowBase = (size_t)blockIdx.y * 128 + wr * 64;
    const int colBase = blockIdx.x * 128 + wc * 64;
#pragma unroll
    for (int tm = 0; tm < 4; tm++)
#pragma unroll
        for (int tn = 0; tn < 4; tn++) {
            int col = colBase + tn * 16 + m16;
            float bv = bias ? bias[col] : 0.f;
#pragma unroll
            for (int r = 0; r < 4; r++) {
                size_t row = rowBase + tm * 16 + quad * 4 + r;
                float v = acc[tm][tn][r] + bv;
                if (RELU) v = fmaxf(v, 0.f);
                C[row * (size_t)ldc + col] = f2bf(v);
            }
        }
}

// scores chunk = Q K^T / 8 + maskbias. zg = zbase + blockIdx.z (= bg*16+h).
__global__ __launch_bounds__(256) void k_gemm_scores(const u16* __restrict__ qproj,
                                                     const u16* __restrict__ kproj,
                                                     const float* __restrict__ maskb,
                                                     u16* __restrict__ scores, int zbase)
{
    __shared__ __align__(16) u16 As[128 * 40];
    __shared__ __align__(16) u16 Bs[128 * 40];
    const int zg = zbase + blockIdx.z;
    const int bg = zg >> 4, h = zg & 15, hbit = h >> 3, hlow = h & 7;
    const size_t base = (size_t)bg * 262144 + (size_t)hbit * 512 + (size_t)hlow * 64;
    const u16* A = qproj + base + (size_t)blockIdx.y * 128 * 1024;
    const u16* B = kproj + base + (size_t)blockIdx.x * 128 * 1024;
    f32x4 acc[4][4];
    gemm_tile<128, 128, 2, 2, 4, 4>(A, 1024, B, 1024, 64, As, Bs, acc);

    const int t = threadIdx.x, lane = t & 63, wave = t >> 6;
    const int wr = wave >> 1, wc = wave & 1, m16 = lane & 15, quad = lane >> 4;
    const int b = bg & 15;
    const int rowBase = blockIdx.y * 128 + wr * 64;
    const int colBase = blockIdx.x * 128 + wc * 64;
    u16* out = scores + (size_t)blockIdx.z * 65536;
#pragma unroll
    for (int tm = 0; tm < 4; tm++)
#pragma unroll
        for (int tn = 0; tn < 4; tn++) {
            int col = colBase + tn * 16 + m16;
            float mb = maskb[b * 256 + col];
#pragma unroll
            for (int r = 0; r < 4; r++) {
                int row = rowBase + tm * 16 + quad * 4 + r;
                out[(size_t)row * 256 + col] = f2bf(acc[tm][tn][r] * 0.125f + mb);
            }
        }
}

// Row softmax in place over 256 cols (one wave per row, 4 rows/block)
__global__ __launch_bounds__(256) void k_softmax(u16* __restrict__ p)
{
    const int wave = threadIdx.x >> 6, lane = threadIdx.x & 63;
    const size_t row = (size_t)blockIdx.x * 4 + wave;
    u16* pr = p + row * 256 + lane * 4;
    us4 v = *(const us4*)pr;
    float f[4];
#pragma unroll
    for (int i = 0; i < 4; i++) f[i] = bf2f(v[i]);
    float m = fmaxf(fmaxf(f[0], f[1]), fmaxf(f[2], f[3]));
#pragma unroll
    for (int off = 32; off > 0; off >>= 1) m = fmaxf(m, __shfl_xor(m, off));
    float s = 0.f;
#pragma unroll
    for (int i = 0; i < 4; i++) { f[i] = __expf(f[i] - m); s += f[i]; }
#pragma unroll
    for (int off = 32; off > 0; off >>= 1) s += __shfl_xor(s, off);
    float inv = 1.0f / s;
    us4 o;
#pragma unroll
    for (int i = 0; i < 4; i++) o[i] = f2bf(f[i] * inv);
    *(us4*)pr = o;
}

// vT[(bg*16+h)*64 + dh][s] = vproj[bg][l=2s+hbit][hlow*64+dh]
__global__ __launch_bounds__(256) void k_transpose_v(const u16* __restrict__ vproj, u16* __restrict__ vT)
{
    __shared__ __align__(16) u16 tile[64 * 72];
    const int lt = blockIdx.x, hlow = blockIdx.y, bg = blockIdx.z;
    const int t = threadIdx.x;
    {
        int rl = t >> 2, c16 = (t & 3) * 16;
        const u16* src = vproj + (size_t)bg * 262144 + (size_t)(lt * 64 + rl) * 512 + hlow * 64 + c16;
        *(us8*)(tile + rl * 72 + c16)     = *(const us8*)src;
        *(us8*)(tile + rl * 72 + c16 + 8) = *(const us8*)(src + 8);
    }
    __syncthreads();
    const int lanej = t & 31, grp = t >> 5;
#pragma unroll
    for (int hbit = 0; hbit < 2; hbit++) {
        int h = hbit * 8 + hlow;
#pragma unroll
        for (int i = 0; i < 8; i++) {
            int dh = grp + i * 8;
            u16 val = tile[(2 * lanej + hbit) * 72 + dh];
            vT[(((size_t)bg * 16 + h) * 64 + dh) * 256 + lt * 32 + lanej] = val;
        }
    }
}

// ctx = P V, scatter into attedpre (B,L,H). zg = zbase + blockIdx.z.
__global__ __launch_bounds__(256) void k_gemm_ctx(const u16* __restrict__ scores,
                                                  const u16* __restrict__ vT,
                                                  u16* __restrict__ attedpre, int zbase)
{
    __shared__ __align__(16) u16 As[128 * 40];
    __shared__ __align__(16) u16 Bs[64 * 40];
    const int zg = zbase + blockIdx.z;
    const u16* A = scores + (size_t)blockIdx.z * 65536 + (size_t)blockIdx.y * 128 * 256;
    const u16* B = vT + (size_t)zg * 16384;
    f32x4 acc[2][4];
    gemm_tile<128, 64, 4, 1, 2, 4>(A, 256, B, 256, 256, As, Bs, acc);

    const int t = threadIdx.x, lane = t & 63, wave = t >> 6;
    const int m16 = lane & 15, quad = lane >> 4;
    const int bg = zg >> 4, h = zg & 15;
    const int g = bg >> 4, b = bg & 15, hbit = h >> 3, hlow = h & 7;
    const int cBase = g * 512 + hlow * 64;
#pragma unroll
    for (int tm = 0; tm < 2; tm++)
#pragma unroll
        for (int tn = 0; tn < 4; tn++) {
            int dh = tn * 16 + m16;
#pragma unroll
            for (int r = 0; r < 4; r++) {
                int s = blockIdx.y * 128 + wave * 32 + tm * 16 + quad * 4 + r;
                int l = 2 * s + hbit;
                attedpre[((size_t)b * 512 + l) * 1024 + cBase + dh] = f2bf(acc[tm][tn][r]);
            }
        }
}

// out = LN(x1 + x2) * gamma + beta over D=1024; one block per row.
// FINAL=0: out is u16 (bf16). FINAL=1: out dtype chosen by *yflag
// (3 -> float32, else bf16) — the harness's d_out dtype follows the input's.
template<int FINAL>
__global__ __launch_bounds__(256) void k_ln(const u16* __restrict__ x1, const u16* __restrict__ x2,
                                            const float* __restrict__ gamma, const float* __restrict__ beta,
                                            void* __restrict__ outv, const int* __restrict__ yflag)
{
    const size_t row = blockIdx.x;
    const int t = threadIdx.x;
    us4 a = *(const us4*)(x1 + row * 1024 + t * 4);
    us4 b = *(const us4*)(x2 + row * 1024 + t * 4);
    float v[4]; float s = 0.f, s2 = 0.f;
#pragma unroll
    for (int i = 0; i < 4; i++) { v[i] = bf2f(a[i]) + bf2f(b[i]); s += v[i]; s2 += v[i] * v[i]; }
#pragma unroll
    for (int off = 32; off > 0; off >>= 1) { s += __shfl_xor(s, off); s2 += __shfl_xor(s2, off); }
    __shared__ float red[8];
    const int lane = t & 63, wave = t >> 6;
    if (lane == 0) { red[wave] = s; red[wave + 4] = s2; }
    __syncthreads();
    s = red[0] + red[1] + red[2] + red[3];
    s2 = red[4] + red[5] + red[6] + red[7];
    float mean = s * (1.0f / 1024.0f);
    float var = fmaxf(s2 * (1.0f / 1024.0f) - mean * mean, 0.0f);
    float rs = rsqrtf(var + 1e-6f);
    float o[4];
#pragma unroll
    for (int i = 0; i < 4; i++) {
        int c = t * 4 + i;
        o[i] = (v[i] - mean) * rs * gamma[c] + beta[c];
    }
    bool f32out = FINAL && yflag && (*yflag == 3);
    if (f32out) {
        float* out = (float*)outv;
#pragma unroll
        for (int i = 0; i < 4; i++) out[row * 1024 + t * 4 + i] = o[i];
    } else {
        u16* out = (u16*)outv;
        us4 ov;
#pragma unroll
        for (int i = 0; i < 4; i++) ov[i] = f2bf(o[i]);
        *(us4*)(out + row * 1024 + t * 4) = ov;
    }
}

// ---------------------------------------------------------------------------
extern "C" void kernel_launch(void* const* d_in, const int* in_sizes, int n_in,
                              void* d_out, int out_size, void* d_ws, size_t ws_size,
                              hipStream_t stream)
{
    (void)in_sizes; (void)n_in; (void)out_size; (void)ws_size;
    const void* y    = d_in[0];
    const void* mask = d_in[1];
    const void* Wv = d_in[2];  const void* bv = d_in[3];
    const void* Wk = d_in[4];  const void* bk = d_in[5];
    const void* Wq = d_in[6];  const void* bq = d_in[7];
    const void* Wm = d_in[8];  const void* bm = d_in[9];
    const void* W1 = d_in[10]; const void* b1 = d_in[11];
    const void* W2 = d_in[12]; const void* b2 = d_in[13];
    const void* g1 = d_in[14]; const void* be1 = d_in[15];
    const void* g2 = d_in[16]; const void* be2 = d_in[17];

    char* ws = (char*)d_ws;
    size_t off = 0;
    auto alloc = [&](size_t bytes) { void* p = ws + off; off = (off + bytes + 255) & ~(size_t)255; return p; };

    int*   flags = (int*)alloc(32 * 4);   // flags[i] = dtype of d_in[i]
    float* maskb = (float*)alloc(16 * 256 * 4);
    float* par   = (float*)alloc(11264 * 4);
    u16* WqT  = (u16*)alloc((size_t)262144 * 2);
    u16* WkT  = (u16*)alloc((size_t)262144 * 2);
    u16* WvT  = (u16*)alloc((size_t)262144 * 2);
    u16* WmT  = (u16*)alloc((size_t)1048576 * 2);
    u16* W1T  = (u16*)alloc((size_t)4194304 * 2);
    u16* W2T  = (u16*)alloc((size_t)1048576 * 2);
    u16* y_c  = (u16*)alloc((size_t)8388608 * 2);
    u16* slotA = (u16*)alloc((size_t)8388608 * 2);   // qproj -> mergeout
    u16* slotB = (u16*)alloc((size_t)8388608 * 2);   // kproj -> y1
    u16* slotC = (u16*)alloc((size_t)8388608 * 2);   // vT -> h1 chunk
    u16* slotD = (u16*)alloc((size_t)8388608 * 2);   // vproj -> attedpre -> ffout
    u16* sch   = (u16*)alloc((size_t)4194304 * 2);   // scores chunk (64 z)

    float* p_bq  = par + 0;
    float* p_bk  = par + 512;
    float* p_bv  = par + 1024;
    float* p_bm  = par + 1536;
    float* p_b1  = par + 2560;
    float* p_b2  = par + 6656;
    float* p_g1  = par + 7168;
    float* p_be1 = par + 8192;
    float* p_g2  = par + 9216;
    float* p_be2 = par + 10240;

    // per-tensor dtype detection (flags[i] for d_in[i])
    k_detect_mask<<<1, 256, 0, stream>>>(mask, flags + 1);
    {
        const void* srcs[18] = {y, mask, Wv, bv, Wk, bk, Wq, bq, Wm, bm, W1, b1, W2, b2, g1, be1, g2, be2};
        const int   nele[18] = {8388608, 4096, 262144, 512, 262144, 512, 262144, 512, 1048576, 1024,
                                4194304, 4096, 1048576, 512, 1024, 1024, 1024, 1024};
        for (int i = 0; i < 18; i++) {
            if (i == 1) continue;
            int nw = nele[i] < 4096 ? nele[i] : 4096;
            k_detect_f<<<1, 256, 0, stream>>>(srcs[i], nw, flags + i);
        }
    }

    k_expand_mask<<<16, 256, 0, stream>>>(mask, flags + 1, maskb);
    k_convert_bf<<<32768, 256, 0, stream>>>(y, y_c, 8388608, flags + 0);

    k_transpose_bf<<<1024, 256, 0, stream>>>(Wq, WqT, 512, 512, flags + 6);
    k_transpose_bf<<<1024, 256, 0, stream>>>(Wk, WkT, 512, 512, flags + 4);
    k_transpose_bf<<<1024, 256, 0, stream>>>(Wv, WvT, 512, 512, flags + 2);
    k_transpose_bf<<<4096, 256, 0, stream>>>(Wm, WmT, 1024, 1024, flags + 8);
    k_transpose_bf<<<16384, 256, 0, stream>>>(W1, W1T, 1024, 4096, flags + 10);
    k_transpose_bf<<<4096, 256, 0, stream>>>(W2, W2T, 2048, 512, flags + 12);

    k_convert_f32<<<2, 256, 0, stream>>>(bq, p_bq, 512, flags + 7);
    k_convert_f32<<<2, 256, 0, stream>>>(bk, p_bk, 512, flags + 5);
    k_convert_f32<<<2, 256, 0, stream>>>(bv, p_bv, 512, flags + 3);
    k_convert_f32<<<4, 256, 0, stream>>>(bm, p_bm, 1024, flags + 9);
    k_convert_f32<<<16, 256, 0, stream>>>(b1, p_b1, 4096, flags + 11);
    k_convert_f32<<<2, 256, 0, stream>>>(b2, p_b2, 512, flags + 13);
    k_convert_f32<<<4, 256, 0, stream>>>(g1, p_g1, 1024, flags + 14);
    k_convert_f32<<<4, 256, 0, stream>>>(be1, p_be1, 1024, flags + 15);
    k_convert_f32<<<4, 256, 0, stream>>>(g2, p_g2, 1024, flags + 16);
    k_convert_f32<<<4, 256, 0, stream>>>(be2, p_be2, 1024, flags + 17);

    u16* qproj = slotA;
    u16* kproj = slotB;
    u16* vproj = slotD;
    u16* vT    = slotC;

    // QKV projections: per group g, A = y_c + g*512 (lda 1024), M=8192, N=512, K=512
    for (int g = 0; g < 2; g++) {
        k_gemm_std<false><<<dim3(4, 64), 256, 0, stream>>>(y_c + g * 512, 1024, WqT, 512, p_bq,
                                                           qproj + (size_t)g * 4194304, 512, 512);
        k_gemm_std<false><<<dim3(4, 64), 256, 0, stream>>>(y_c + g * 512, 1024, WkT, 512, p_bk,
                                                           kproj + (size_t)g * 4194304, 512, 512);
        k_gemm_std<false><<<dim3(4, 64), 256, 0, stream>>>(y_c + g * 512, 1024, WvT, 512, p_bv,
                                                           vproj + (size_t)g * 4194304, 512, 512);
    }

    k_transpose_v<<<dim3(8, 8, 32), 256, 0, stream>>>(vproj, vT);
    u16* attedpre = slotD;   // vproj dead

    // attention in 8 z-chunks of 64 (scores chunk = 8 MB)
    for (int c = 0; c < 8; c++) {
        int zbase = c * 64;
        k_gemm_scores<<<dim3(2, 2, 64), 256, 0, stream>>>(qproj, kproj, maskb, sch, zbase);
        k_softmax<<<4096, 256, 0, stream>>>(sch);
        k_gemm_ctx<<<dim3(1, 2, 64), 256, 0, stream>>>(sch, vT, attedpre, zbase);
    }

    u16* mergeout = slotA;   // qproj dead
    k_gemm_std<false><<<dim3(8, 64), 256, 0, stream>>>(attedpre, 1024, WmT, 1024, p_bm, mergeout, 1024, 1024);

    u16* y1 = slotB;         // kproj dead
    k_ln<0><<<8192, 256, 0, stream>>>(y_c, mergeout, p_g1, p_be1, y1, nullptr);

    u16* h1c   = slotC;      // vT dead
    u16* ffout = slotD;      // attedpre dead
    for (int c = 0; c < 4; c++) {
        const u16* Ac = y1 + (size_t)c * 2048 * 1024;
        k_gemm_std<true><<<dim3(32, 16), 256, 0, stream>>>(Ac, 1024, W1T, 1024, p_b1, h1c, 4096, 1024);
        for (int g = 0; g < 2; g++) {
            k_gemm_std<false><<<dim3(4, 16), 256, 0, stream>>>(h1c + g * 2048, 4096, W2T, 2048, p_b2,
                                                               ffout + (size_t)c * 2048 * 1024 + g * 512, 1024, 2048);
        }
    }

    // final LN: output dtype follows detected input dtype (f32 vs bf16)
    k_ln<1><<<8192, 256, 0, stream>>>(y1, ffout, p_g2, p_be2, d_out, flags + 0);
}

// Round 5
// 512.054 us; speedup vs baseline: 2.3865x; 2.3865x over previous
//
#include <hip/hip_runtime.h>
#include <stdint.h>

typedef unsigned short u16;
using us8   = __attribute__((ext_vector_type(8))) unsigned short;
using us4   = __attribute__((ext_vector_type(4))) unsigned short;
using bf16x8 = __attribute__((ext_vector_type(8))) __bf16;
using f32x4 = __attribute__((ext_vector_type(4))) float;

#define DEV static __device__ __forceinline__

DEV float bf2f(u16 u) { union { uint32_t i; float f; } v; v.i = (uint32_t)u << 16; return v.f; }
DEV u16 f2bf(float f) {
    union { float f; uint32_t i; } v; v.f = f;
    uint32_t u = v.i;
    return (u16)((u + 0x7FFFu + ((u >> 16) & 1u)) >> 16);
}

// ---------------------------------------------------------------------------
// Fused dtype detection: 18 blocks, one per input tensor.
// flags[i]: for floats 2=bf16, 3=f32; for mask (i==1) 0=i8,1=i32,2=bf16,3=f32.
// ---------------------------------------------------------------------------
struct DetectArgs { const void* p[18]; int nw[18]; };

__global__ __launch_bounds__(256) void k_detect_all(DetectArgs a, int* flags)
{
    const int b = blockIdx.x;
    const int t = threadIdx.x;
    __shared__ int cnt[4];
    if (t < 4) cnt[t] = 0;
    __syncthreads();
    if (b == 1) {
        const uint8_t* m = (const uint8_t*)a.p[1];
        int c0 = 0, c1 = 0, c2 = 0, c3 = 0;
        for (int i = t; i < 4096; i += 256) {
            uint8_t v = m[i];
            int mod = i & 3;
            if (v == 0x3F && mod == 1) c0++;
            if (v == 0x3F && mod == 3) c1++;
            if (v == 1 && mod != 0) c2++;
            if (v == 1 && mod == 0) c3++;
        }
        atomicAdd(&cnt[0], c0); atomicAdd(&cnt[1], c1); atomicAdd(&cnt[2], c2); atomicAdd(&cnt[3], c3);
        __syncthreads();
        if (t == 0) {
            int mf;
            if (cnt[0] > 0) mf = 2;
            else if (cnt[1] > 0) mf = 3;
            else if (cnt[2] > 0) mf = 0;
            else if (cnt[3] > 0) mf = 1;
            else mf = 0;
            flags[1] = mf;
        }
    } else {
        const u16* p = (const u16*)a.p[b];
        int nw = a.nw[b];
        int nze = 0, pe = 0, nzo = 0;
        for (int i = t; i < nw; i += 256) {
            u16 w = p[i];
            if (w == 0) continue;
            int e = (w >> 7) & 0xFF;
            bool pl = (e >= 90 && e <= 140);
            if ((i & 1) == 0) { nze++; if (pl) pe++; }
            else nzo++;
        }
        atomicAdd(&cnt[0], nze); atomicAdd(&cnt[1], pe); atomicAdd(&cnt[2], nzo);
        __syncthreads();
        if (t == 0) {
            int f;
            if (cnt[0] > 0)      f = (cnt[1] * 10 >= cnt[0] * 6) ? 2 : 3;
            else if (cnt[2] > 0) f = 3;
            else                 f = 2;
            flags[b] = f;
        }
    }
}

__global__ __launch_bounds__(256) void k_expand_mask(const void* mask, const int* flag, float* mb)
{
    int i = blockIdx.x * 256 + threadIdx.x;
    if (i >= 4096) return;
    int f = *flag;
    bool on;
    if (f == 0)      on = ((const uint8_t*)mask)[i]  != 0;
    else if (f == 1) on = ((const int*)mask)[i]      != 0;
    else if (f == 2) on = ((const u16*)mask)[i]      != 0;
    else             on = ((const uint32_t*)mask)[i] != 0;
    mb[i] = on ? -1e9f : 0.0f;
}

__global__ __launch_bounds__(256) void k_convert_bf(const void* src, u16* dst, int n, const int* flag)
{
    int i = blockIdx.x * 256 + threadIdx.x;
    if (i >= n) return;
    if (*flag == 2) dst[i] = ((const u16*)src)[i];
    else            dst[i] = f2bf(((const float*)src)[i]);
}

// ---------------------------------------------------------------------------
// Fused LDS-tiled weight transposes: 6 matrices in one launch.
// dst (C x R) = src(R x C)^T, bf16 out. 32x32 tiles, 256 threads.
// ---------------------------------------------------------------------------
struct TransArgs { const void* src[6]; u16* dst[6]; int R[6]; int C[6]; int flagidx[6]; int tstart[7]; };

__global__ __launch_bounds__(256) void k_transpose_all(TransArgs a, const int* flags)
{
    const int tb = blockIdx.x;
    int s = 0;
    while (tb >= a.tstart[s + 1]) s++;
    const int lt = tb - a.tstart[s];
    const int R = a.R[s], C = a.C[s];
    const int tilesX = C >> 5;
    const int ti = lt / tilesX, tj = lt - ti * tilesX;
    const int r0 = ti * 32, c0 = tj * 32;
    const bool isbf = (flags[a.flagidx[s]] == 2);
    const int t = threadIdx.x;
    const int j = t & 31, i0 = t >> 5;
    __shared__ u16 tile[32][33];
#pragma unroll
    for (int p = 0; p < 4; p++) {
        int r = r0 + i0 + p * 8;
        size_t idx = (size_t)r * C + c0 + j;
        u16 v = isbf ? ((const u16*)a.src[s])[idx] : f2bf(((const float*)a.src[s])[idx]);
        tile[i0 + p * 8][j] = v;
    }
    __syncthreads();
    u16* dst = a.dst[s];
#pragma unroll
    for (int p = 0; p < 4; p++) {
        int c = i0 + p * 8;
        dst[(size_t)(c0 + c) * R + r0 + j] = tile[j][c];
    }
}

// ---------------------------------------------------------------------------
// Fused param (bias/gain) converts to fp32: 10 contiguous segments -> par[]
// ---------------------------------------------------------------------------
struct ConvArgs { const void* src[10]; int flagidx[10]; int off[10]; int n[10]; };

__global__ __launch_bounds__(256) void k_convert_params(ConvArgs a, const int* flags, float* par)
{
    int i = blockIdx.x * 256 + threadIdx.x;
    if (i >= 11264) return;
    int s = 0;
    while (s < 9 && i >= a.off[s] + a.n[s]) s++;
    int j = i - a.off[s];
    float v;
    if (flags[a.flagidx[s]] == 2) v = bf2f(((const u16*)a.src[s])[j]);
    else                          v = ((const float*)a.src[s])[j];
    par[i] = v;
}

// ---------------------------------------------------------------------------
// MFMA GEMM core: C(M x N) = A(M x K, row-major, lda) * B(K x N), B given
// TRANSPOSED (Bt: N x K row-major, ldb). BK=32, fp32 accum, LDS rows pad 40.
// ---------------------------------------------------------------------------
template<int BM, int BN, int WR, int WC, int TM, int TN>
DEV void gemm_tile(const u16* __restrict__ A, int lda,
                   const u16* __restrict__ Bt, int ldb, int K,
                   u16* As, u16* Bs, f32x4 (&acc)[TM][TN])
{
    constexpr int NT = WR * WC * 64;
    const int t = threadIdx.x;
    const int lane = t & 63;
    const int wave = t >> 6;
    const int wr = wave / WC;
    const int wc = wave % WC;
    const int m16 = lane & 15;
    const int quad = lane >> 4;

#pragma unroll
    for (int i = 0; i < TM; i++)
#pragma unroll
        for (int j = 0; j < TN; j++) {
            acc[i][j][0] = 0.f; acc[i][j][1] = 0.f; acc[i][j][2] = 0.f; acc[i][j][3] = 0.f;
        }

    for (int kb = 0; kb < K; kb += 32) {
#pragma unroll
        for (int pass = 0; pass < (BM * 4) / NT; pass++) {
            int idx = t + pass * NT;
            int r = idx >> 2, c8 = (idx & 3) << 3;
            *(us8*)(As + r * 40 + c8) = *(const us8*)(A + (size_t)r * lda + kb + c8);
        }
#pragma unroll
        for (int pass = 0; pass < (BN * 4) / NT; pass++) {
            int idx = t + pass * NT;
            int r = idx >> 2, c8 = (idx & 3) << 3;
            *(us8*)(Bs + r * 40 + c8) = *(const us8*)(Bt + (size_t)r * ldb + kb + c8);
        }
        __syncthreads();
        bf16x8 af[TM], bfr[TN];
#pragma unroll
        for (int i = 0; i < TM; i++)
            af[i] = *(const bf16x8*)(As + (wr * TM * 16 + i * 16 + m16) * 40 + quad * 8);
#pragma unroll
        for (int j = 0; j < TN; j++)
            bfr[j] = *(const bf16x8*)(Bs + (wc * TN * 16 + j * 16 + m16) * 40 + quad * 8);
#pragma unroll
        for (int i = 0; i < TM; i++)
#pragma unroll
            for (int j = 0; j < TN; j++)
                acc[i][j] = __builtin_amdgcn_mfma_f32_16x16x32_bf16(af[i], bfr[j], acc[i][j], 0, 0, 0);
        __syncthreads();
    }
}

template<bool RELU>
__global__ __launch_bounds__(256) void k_gemm_std(const u16* __restrict__ A, int lda,
                                                  const u16* __restrict__ Bt, int ldb,
                                                  const float* __restrict__ bias,
                                                  u16* __restrict__ C, int ldc, int K)
{
    __shared__ __align__(16) u16 As[128 * 40];
    __shared__ __align__(16) u16 Bs[128 * 40];
    const u16* Ab = A + (size_t)blockIdx.y * 128 * lda;
    const u16* Bb = Bt + (size_t)blockIdx.x * 128 * ldb;
    f32x4 acc[4][4];
    gemm_tile<128, 128, 2, 2, 4, 4>(Ab, lda, Bb, ldb, K, As, Bs, acc);

    const int t = threadIdx.x, lane = t & 63, wave = t >> 6;
    const int wr = wave >> 1, wc = wave & 1, m16 = lane & 15, quad = lane >> 4;
    const size_t rowBase = (size_t)blockIdx.y * 128 + wr * 64;
    const int colBase = blockIdx.x * 128 + wc * 64;
#pragma unroll
    for (int tm = 0; tm < 4; tm++)
#pragma unroll
        for (int tn = 0; tn < 4; tn++) {
            int col = colBase + tn * 16 + m16;
            float bv = bias ? bias[col] : 0.f;
#pragma unroll
            for (int r = 0; r < 4; r++) {
                size_t row = rowBase + tm * 16 + quad * 4 + r;
                float v = acc[tm][tn][r] + bv;
                if (RELU) v = fmaxf(v, 0.f);
                C[row * (size_t)ldc + col] = f2bf(v);
            }
        }
}

// Fused QKV: grid (4, 64, 6); z -> (g = z/3, mat = z%3). M=8192 N=512 K=512.
__global__ __launch_bounds__(256) void k_gemm_qkv(const u16* __restrict__ y_c,
                                                  const u16* __restrict__ WqT,
                                                  const u16* __restrict__ WkT,
                                                  const u16* __restrict__ WvT,
                                                  const float* __restrict__ biases,  // bq@0, bk@512, bv@1024
                                                  u16* __restrict__ qp, u16* __restrict__ kp, u16* __restrict__ vp)
{
    __shared__ __align__(16) u16 As[128 * 40];
    __shared__ __align__(16) u16 Bs[128 * 40];
    const int z = blockIdx.z;
    const int mat = z % 3, g = z / 3;
    const u16* Bt = (mat == 0) ? WqT : (mat == 1) ? WkT : WvT;
    u16* out = ((mat == 0) ? qp : (mat == 1) ? kp : vp) + (size_t)g * 4194304;
    const float* bias = biases + mat * 512;
    const u16* Ab = y_c + g * 512 + (size_t)blockIdx.y * 128 * 1024;
    const u16* Bb = Bt + (size_t)blockIdx.x * 128 * 512;
    f32x4 acc[4][4];
    gemm_tile<128, 128, 2, 2, 4, 4>(Ab, 1024, Bb, 512, 512, As, Bs, acc);

    const int t = threadIdx.x, lane = t & 63, wave = t >> 6;
    const int wr = wave >> 1, wc = wave & 1, m16 = lane & 15, quad = lane >> 4;
    const size_t rowBase = (size_t)blockIdx.y * 128 + wr * 64;
    const int colBase = blockIdx.x * 128 + wc * 64;
#pragma unroll
    for (int tm = 0; tm < 4; tm++)
#pragma unroll
        for (int tn = 0; tn < 4; tn++) {
            int col = colBase + tn * 16 + m16;
            float bv = bias[col];
#pragma unroll
            for (int r = 0; r < 4; r++) {
                size_t row = rowBase + tm * 16 + quad * 4 + r;
                out[row * 512 + col] = f2bf(acc[tm][tn][r] + bv);
            }
        }
}

// ---------------------------------------------------------------------------
// Fused scores + mask + softmax -> P (bf16). Grid (4, 512): x = 64-row tile,
// y = z (bg*16+h). Block computes 64 rows x all 256 cols, softmaxes in-block.
// ---------------------------------------------------------------------------
__global__ __launch_bounds__(256) void k_attn_scores(const u16* __restrict__ qproj,
                                                     const u16* __restrict__ kproj,
                                                     const float* __restrict__ maskb,
                                                     u16* __restrict__ P)
{
    __shared__ __align__(16) u16 As[64 * 40];
    __shared__ __align__(16) u16 Bs[256 * 40];
    __shared__ float smax[64][5];
    __shared__ float ssum[64][5];
    const int rt = blockIdx.x;
    const int z = blockIdx.y;
    const int bg = z >> 4, h = z & 15, hbit = h >> 3, hlow = h & 7;
    const int b = bg & 15;
    const size_t base = (size_t)bg * 262144 + (size_t)hbit * 512 + (size_t)hlow * 64;
    const u16* A = qproj + base + (size_t)rt * 64 * 1024;
    const u16* B = kproj + base;
    f32x4 acc[4][4];
    gemm_tile<64, 256, 1, 4, 4, 4>(A, 1024, B, 1024, 64, As, Bs, acc);

    const int t = threadIdx.x, lane = t & 63, wc = t >> 6;
    const int m16 = lane & 15, quad = lane >> 4;

    // scale + mask
    float mb[4];
#pragma unroll
    for (int j = 0; j < 4; j++) mb[j] = maskb[b * 256 + wc * 64 + j * 16 + m16];
#pragma unroll
    for (int i = 0; i < 4; i++)
#pragma unroll
        for (int j = 0; j < 4; j++)
#pragma unroll
            for (int r = 0; r < 4; r++)
                acc[i][j][r] = acc[i][j][r] * 0.125f + mb[j];

    // row max (per lane: rows i*16 + quad*4 + r)
#pragma unroll
    for (int i = 0; i < 4; i++)
#pragma unroll
        for (int r = 0; r < 4; r++) {
            float mm = fmaxf(fmaxf(acc[i][0][r], acc[i][1][r]), fmaxf(acc[i][2][r], acc[i][3][r]));
            mm = fmaxf(mm, __shfl_xor(mm, 1));
            mm = fmaxf(mm, __shfl_xor(mm, 2));
            mm = fmaxf(mm, __shfl_xor(mm, 4));
            mm = fmaxf(mm, __shfl_xor(mm, 8));
            if (m16 == 0) smax[i * 16 + quad * 4 + r][wc] = mm;
        }
    __syncthreads();
    float mrow[4][4];
#pragma unroll
    for (int i = 0; i < 4; i++)
#pragma unroll
        for (int r = 0; r < 4; r++) {
            int row = i * 16 + quad * 4 + r;
            mrow[i][r] = fmaxf(fmaxf(smax[row][0], smax[row][1]), fmaxf(smax[row][2], smax[row][3]));
        }
    // exp + row sum
#pragma unroll
    for (int i = 0; i < 4; i++)
#pragma unroll
        for (int r = 0; r < 4; r++) {
            float s = 0.f;
#pragma unroll
            for (int j = 0; j < 4; j++) {
                float e = __expf(acc[i][j][r] - mrow[i][r]);
                acc[i][j][r] = e;
                s += e;
            }
            s += __shfl_xor(s, 1);
            s += __shfl_xor(s, 2);
            s += __shfl_xor(s, 4);
            s += __shfl_xor(s, 8);
            if (m16 == 0) ssum[i * 16 + quad * 4 + r][wc] = s;
        }
    __syncthreads();
    u16* out = P + (size_t)z * 65536 + (size_t)rt * 64 * 256;
#pragma unroll
    for (int i = 0; i < 4; i++)
#pragma unroll
        for (int r = 0; r < 4; r++) {
            int row = i * 16 + quad * 4 + r;
            float inv = 1.0f / (ssum[row][0] + ssum[row][1] + ssum[row][2] + ssum[row][3]);
#pragma unroll
            for (int j = 0; j < 4; j++) {
                int col = wc * 64 + j * 16 + m16;
                out[(size_t)row * 256 + col] = f2bf(acc[i][j][r] * inv);
            }
        }
}

// vT[(bg*16+h)*64 + dh][s] = vproj[bg][l=2s+hbit][hlow*64+dh]
__global__ __launch_bounds__(256) void k_transpose_v(const u16* __restrict__ vproj, u16* __restrict__ vT)
{
    __shared__ __align__(16) u16 tile[64 * 72];
    const int lt = blockIdx.x, hlow = blockIdx.y, bg = blockIdx.z;
    const int t = threadIdx.x;
    {
        int rl = t >> 2, c16 = (t & 3) * 16;
        const u16* src = vproj + (size_t)bg * 262144 + (size_t)(lt * 64 + rl) * 512 + hlow * 64 + c16;
        *(us8*)(tile + rl * 72 + c16)     = *(const us8*)src;
        *(us8*)(tile + rl * 72 + c16 + 8) = *(const us8*)(src + 8);
    }
    __syncthreads();
    const int lanej = t & 31, grp = t >> 5;
#pragma unroll
    for (int hbit = 0; hbit < 2; hbit++) {
        int h = hbit * 8 + hlow;
#pragma unroll
        for (int i = 0; i < 8; i++) {
            int dh = grp + i * 8;
            u16 val = tile[(2 * lanej + hbit) * 72 + dh];
            vT[(((size_t)bg * 16 + h) * 64 + dh) * 256 + lt * 32 + lanej] = val;
        }
    }
}

// ctx = P V, scatter into attedpre (B,L,H). Grid (2, 512): x = 128-row tile, y = z.
__global__ __launch_bounds__(256) void k_gemm_ctx(const u16* __restrict__ P,
                                                  const u16* __restrict__ vT,
                                                  u16* __restrict__ attedpre)
{
    __shared__ __align__(16) u16 As[128 * 40];
    __shared__ __align__(16) u16 Bs[64 * 40];
    const int z = blockIdx.y;
    const u16* A = P + (size_t)z * 65536 + (size_t)blockIdx.x * 128 * 256;
    const u16* B = vT + (size_t)z * 16384;
    f32x4 acc[2][4];
    gemm_tile<128, 64, 4, 1, 2, 4>(A, 256, B, 256, 256, As, Bs, acc);

    const int t = threadIdx.x, lane = t & 63, wave = t >> 6;
    const int m16 = lane & 15, quad = lane >> 4;
    const int bg = z >> 4, h = z & 15;
    const int g = bg >> 4, b = bg & 15, hbit = h >> 3, hlow = h & 7;
    const int cBase = g * 512 + hlow * 64;
#pragma unroll
    for (int tm = 0; tm < 2; tm++)
#pragma unroll
        for (int tn = 0; tn < 4; tn++) {
            int dh = tn * 16 + m16;
#pragma unroll
            for (int r = 0; r < 4; r++) {
                int s = blockIdx.x * 128 + wave * 32 + tm * 16 + quad * 4 + r;
                int l = 2 * s + hbit;
                attedpre[((size_t)b * 512 + l) * 1024 + cBase + dh] = f2bf(acc[tm][tn][r]);
            }
        }
}

// Fused grouped FFN2: grid (8, 64). x -> (g = x>>2, xn = x&3). out += group offset.
__global__ __launch_bounds__(256) void k_gemm_ffn2(const u16* __restrict__ h1,
                                                   const u16* __restrict__ W2T,
                                                   const float* __restrict__ b2,
                                                   u16* __restrict__ out)
{
    __shared__ __align__(16) u16 As[128 * 40];
    __shared__ __align__(16) u16 Bs[128 * 40];
    const int xi = blockIdx.x;
    const int g = xi >> 2, xn = xi & 3;
    const u16* Ab = h1 + (size_t)blockIdx.y * 128 * 4096 + g * 2048;
    const u16* Bb = W2T + (size_t)xn * 128 * 2048;
    f32x4 acc[4][4];
    gemm_tile<128, 128, 2, 2, 4, 4>(Ab, 4096, Bb, 2048, 2048, As, Bs, acc);

    const int t = threadIdx.x, lane = t & 63, wave = t >> 6;
    const int wr = wave >> 1, wc = wave & 1, m16 = lane & 15, quad = lane >> 4;
    const size_t rowBase = (size_t)blockIdx.y * 128 + wr * 64;
    const int colg = xn * 128 + wc * 64;   // column within group (0..511)
#pragma unroll
    for (int tm = 0; tm < 4; tm++)
#pragma unroll
        for (int tn = 0; tn < 4; tn++) {
            int cg = colg + tn * 16 + m16;
            float bv = b2[cg];
#pragma unroll
            for (int r = 0; r < 4; r++) {
                size_t row = rowBase + tm * 16 + quad * 4 + r;
                out[row * 1024 + g * 512 + cg] = f2bf(acc[tm][tn][r] + bv);
            }
        }
}

// out = LN(x1 + x2) * gamma + beta over D=1024; one block per row.
// FINAL=1: out dtype follows *yflag (3 -> f32, else bf16).
template<int FINAL>
__global__ __launch_bounds__(256) void k_ln(const u16* __restrict__ x1, const u16* __restrict__ x2,
                                            const float* __restrict__ gamma, const float* __restrict__ beta,
                                            void* __restrict__ outv, const int* __restrict__ yflag)
{
    const size_t row = blockIdx.x;
    const int t = threadIdx.x;
    us4 a = *(const us4*)(x1 + row * 1024 + t * 4);
    us4 b = *(const us4*)(x2 + row * 1024 + t * 4);
    float v[4]; float s = 0.f, s2 = 0.f;
#pragma unroll
    for (int i = 0; i < 4; i++) { v[i] = bf2f(a[i]) + bf2f(b[i]); s += v[i]; s2 += v[i] * v[i]; }
#pragma unroll
    for (int off = 32; off > 0; off >>= 1) { s += __shfl_xor(s, off); s2 += __shfl_xor(s2, off); }
    __shared__ float red[8];
    const int lane = t & 63, wave = t >> 6;
    if (lane == 0) { red[wave] = s; red[wave + 4] = s2; }
    __syncthreads();
    s = red[0] + red[1] + red[2] + red[3];
    s2 = red[4] + red[5] + red[6] + red[7];
    float mean = s * (1.0f / 1024.0f);
    float var = fmaxf(s2 * (1.0f / 1024.0f) - mean * mean, 0.0f);
    float rs = rsqrtf(var + 1e-6f);
    float o[4];
#pragma unroll
    for (int i = 0; i < 4; i++) {
        int c = t * 4 + i;
        o[i] = (v[i] - mean) * rs * gamma[c] + beta[c];
    }
    bool f32out = FINAL && yflag && (*yflag == 3);
    if (f32out) {
        float* out = (float*)outv;
#pragma unroll
        for (int i = 0; i < 4; i++) out[row * 1024 + t * 4 + i] = o[i];
    } else {
        u16* out = (u16*)outv;
        us4 ov;
#pragma unroll
        for (int i = 0; i < 4; i++) ov[i] = f2bf(o[i]);
        *(us4*)(out + row * 1024 + t * 4) = ov;
    }
}

// ---------------------------------------------------------------------------
extern "C" void kernel_launch(void* const* d_in, const int* in_sizes, int n_in,
                              void* d_out, int out_size, void* d_ws, size_t ws_size,
                              hipStream_t stream)
{
    (void)in_sizes; (void)n_in; (void)out_size; (void)ws_size;
    const void* y    = d_in[0];
    const void* mask = d_in[1];
    const void* Wv = d_in[2];  const void* bv = d_in[3];
    const void* Wk = d_in[4];  const void* bk = d_in[5];
    const void* Wq = d_in[6];  const void* bq = d_in[7];
    const void* Wm = d_in[8];  const void* bm = d_in[9];
    const void* W1 = d_in[10]; const void* b1 = d_in[11];
    const void* W2 = d_in[12]; const void* b2 = d_in[13];
    const void* g1 = d_in[14]; const void* be1 = d_in[15];
    const void* g2 = d_in[16]; const void* be2 = d_in[17];

    char* ws = (char*)d_ws;
    size_t off = 0;
    auto alloc = [&](size_t bytes) { void* p = ws + off; off = (off + bytes + 255) & ~(size_t)255; return p; };

    int*   flags = (int*)alloc(32 * 4);
    float* maskb = (float*)alloc(16 * 256 * 4);
    float* par   = (float*)alloc(11264 * 4);
    u16* WqT  = (u16*)alloc((size_t)262144 * 2);
    u16* WkT  = (u16*)alloc((size_t)262144 * 2);
    u16* WvT  = (u16*)alloc((size_t)262144 * 2);
    u16* WmT  = (u16*)alloc((size_t)1048576 * 2);
    u16* W1T  = (u16*)alloc((size_t)4194304 * 2);
    u16* W2T  = (u16*)alloc((size_t)1048576 * 2);
    u16* y_c  = (u16*)alloc((size_t)8388608 * 2);
    u16* slotA = (u16*)alloc((size_t)8388608 * 2);   // qproj -> mergeout
    u16* slotB = (u16*)alloc((size_t)8388608 * 2);   // kproj -> y1
    u16* slotC = (u16*)alloc((size_t)8388608 * 2);   // vT -> ffout
    u16* slotD = (u16*)alloc((size_t)8388608 * 2);   // vproj -> attedpre
    u16* Pbig  = (u16*)alloc((size_t)33554432 * 2);  // P (64 MB) -> h1 (32 MB)

    float* p_bm  = par + 1536;
    float* p_b1  = par + 2560;
    float* p_b2  = par + 6656;
    float* p_g1  = par + 7168;
    float* p_be1 = par + 8192;
    float* p_g2  = par + 9216;
    float* p_be2 = par + 10240;

    // --- fused dtype detection ---
    DetectArgs da;
    {
        const void* srcs[18] = {y, mask, Wv, bv, Wk, bk, Wq, bq, Wm, bm, W1, b1, W2, b2, g1, be1, g2, be2};
        const int   nele[18] = {8388608, 4096, 262144, 512, 262144, 512, 262144, 512, 1048576, 1024,
                                4194304, 4096, 1048576, 512, 1024, 1024, 1024, 1024};
        for (int i = 0; i < 18; i++) { da.p[i] = srcs[i]; da.nw[i] = nele[i] < 4096 ? nele[i] : 4096; }
    }
    k_detect_all<<<18, 256, 0, stream>>>(da, flags);

    k_expand_mask<<<16, 256, 0, stream>>>(mask, flags + 1, maskb);
    k_convert_bf<<<32768, 256, 0, stream>>>(y, y_c, 8388608, flags + 0);

    // --- fused weight transposes ---
    TransArgs ta;
    {
        const void* s6[6] = {Wq, Wk, Wv, Wm, W1, W2};
        u16* d6[6] = {WqT, WkT, WvT, WmT, W1T, W2T};
        int R6[6] = {512, 512, 512, 1024, 1024, 2048};
        int C6[6] = {512, 512, 512, 1024, 4096, 512};
        int f6[6] = {6, 4, 2, 8, 10, 12};
        int ts[7] = {0, 256, 512, 768, 1792, 5888, 6912};
        for (int i = 0; i < 6; i++) { ta.src[i] = s6[i]; ta.dst[i] = d6[i]; ta.R[i] = R6[i]; ta.C[i] = C6[i]; ta.flagidx[i] = f6[i]; }
        for (int i = 0; i < 7; i++) ta.tstart[i] = ts[i];
    }
    k_transpose_all<<<6912, 256, 0, stream>>>(ta, flags);

    // --- fused param converts ---
    ConvArgs ca;
    {
        const void* s10[10] = {bq, bk, bv, bm, b1, b2, g1, be1, g2, be2};
        int f10[10] = {7, 5, 3, 9, 11, 13, 14, 15, 16, 17};
        int o10[10] = {0, 512, 1024, 1536, 2560, 6656, 7168, 8192, 9216, 10240};
        int n10[10] = {512, 512, 512, 1024, 4096, 512, 1024, 1024, 1024, 1024};
        for (int i = 0; i < 10; i++) { ca.src[i] = s10[i]; ca.flagidx[i] = f10[i]; ca.off[i] = o10[i]; ca.n[i] = n10[i]; }
    }
    k_convert_params<<<44, 256, 0, stream>>>(ca, flags, par);

    u16* qproj = slotA;
    u16* kproj = slotB;
    u16* vT    = slotC;
    u16* vproj = slotD;

    k_gemm_qkv<<<dim3(4, 64, 6), 256, 0, stream>>>(y_c, WqT, WkT, WvT, par, qproj, kproj, vproj);
    k_transpose_v<<<dim3(8, 8, 32), 256, 0, stream>>>(vproj, vT);

    u16* P = Pbig;
    k_attn_scores<<<dim3(4, 512), 256, 0, stream>>>(qproj, kproj, maskb, P);

    u16* attedpre = slotD;   // vproj dead
    k_gemm_ctx<<<dim3(2, 512), 256, 0, stream>>>(P, vT, attedpre);

    u16* mergeout = slotA;   // qproj dead
    k_gemm_std<false><<<dim3(8, 64), 256, 0, stream>>>(attedpre, 1024, WmT, 1024, p_bm, mergeout, 1024, 1024);

    u16* y1 = slotB;         // kproj dead
    k_ln<0><<<8192, 256, 0, stream>>>(y_c, mergeout, p_g1, p_be1, y1, nullptr);

    u16* h1 = Pbig;          // P dead after ctx
    k_gemm_std<true><<<dim3(32, 64), 256, 0, stream>>>(y1, 1024, W1T, 1024, p_b1, h1, 4096, 1024);

    u16* ffout = slotC;      // vT dead
    k_gemm_ffn2<<<dim3(8, 64), 256, 0, stream>>>(h1, W2T, p_b2, ffout);

    k_ln<1><<<8192, 256, 0, stream>>>(y1, ffout, p_g2, p_be2, d_out, flags + 0);
}

// Round 6
// 491.815 us; speedup vs baseline: 2.4847x; 1.0412x over previous
//
#include <hip/hip_runtime.h>
#include <stdint.h>

typedef unsigned short u16;
using us8   = __attribute__((ext_vector_type(8))) unsigned short;
using us4   = __attribute__((ext_vector_type(4))) unsigned short;
using bf16x8 = __attribute__((ext_vector_type(8))) __bf16;
using f32x4 = __attribute__((ext_vector_type(4))) float;

#define DEV static __device__ __forceinline__

DEV float bf2f(u16 u) { union { uint32_t i; float f; } v; v.i = (uint32_t)u << 16; return v.f; }
DEV u16 f2bf(float f) {
    union { float f; uint32_t i; } v; v.f = f;
    uint32_t u = v.i;
    return (u16)((u + 0x7FFFu + ((u >> 16) & 1u)) >> 16);
}

// async global->LDS 16B copy: lane l of the wave writes LDS at (uniform base) + l*16B.
// LDS layout MUST be contiguous in lane order (no padding) — m104/m108.
DEV void async16(const u16* g, u16* ldsbase)
{
    __builtin_amdgcn_global_load_lds((const __attribute__((address_space(1))) void*)g,
                                     (__attribute__((address_space(3))) void*)ldsbase, 16, 0, 0);
}

// ---------------------------------------------------------------------------
// Fused dtype detection: 18 blocks, one per input tensor.
// flags[i]: for floats 2=bf16, 3=f32; for mask (i==1) 0=i8,1=i32,2=bf16,3=f32.
// ---------------------------------------------------------------------------
struct DetectArgs { const void* p[18]; int nw[18]; };

__global__ __launch_bounds__(256) void k_detect_all(DetectArgs a, int* flags)
{
    const int b = blockIdx.x;
    const int t = threadIdx.x;
    __shared__ int cnt[4];
    if (t < 4) cnt[t] = 0;
    __syncthreads();
    if (b == 1) {
        const uint8_t* m = (const uint8_t*)a.p[1];
        int c0 = 0, c1 = 0, c2 = 0, c3 = 0;
        for (int i = t; i < 4096; i += 256) {
            uint8_t v = m[i];
            int mod = i & 3;
            if (v == 0x3F && mod == 1) c0++;
            if (v == 0x3F && mod == 3) c1++;
            if (v == 1 && mod != 0) c2++;
            if (v == 1 && mod == 0) c3++;
        }
        atomicAdd(&cnt[0], c0); atomicAdd(&cnt[1], c1); atomicAdd(&cnt[2], c2); atomicAdd(&cnt[3], c3);
        __syncthreads();
        if (t == 0) {
            int mf;
            if (cnt[0] > 0) mf = 2;
            else if (cnt[1] > 0) mf = 3;
            else if (cnt[2] > 0) mf = 0;
            else if (cnt[3] > 0) mf = 1;
            else mf = 0;
            flags[1] = mf;
        }
    } else {
        const u16* p = (const u16*)a.p[b];
        int nw = a.nw[b];
        int nze = 0, pe = 0, nzo = 0;
        for (int i = t; i < nw; i += 256) {
            u16 w = p[i];
            if (w == 0) continue;
            int e = (w >> 7) & 0xFF;
            bool pl = (e >= 90 && e <= 140);
            if ((i & 1) == 0) { nze++; if (pl) pe++; }
            else nzo++;
        }
        atomicAdd(&cnt[0], nze); atomicAdd(&cnt[1], pe); atomicAdd(&cnt[2], nzo);
        __syncthreads();
        if (t == 0) {
            int f;
            if (cnt[0] > 0)      f = (cnt[1] * 10 >= cnt[0] * 6) ? 2 : 3;
            else if (cnt[2] > 0) f = 3;
            else                 f = 2;
            flags[b] = f;
        }
    }
}

__global__ __launch_bounds__(256) void k_expand_mask(const void* mask, const int* flag, float* mb)
{
    int i = blockIdx.x * 256 + threadIdx.x;
    if (i >= 4096) return;
    int f = *flag;
    bool on;
    if (f == 0)      on = ((const uint8_t*)mask)[i]  != 0;
    else if (f == 1) on = ((const int*)mask)[i]      != 0;
    else if (f == 2) on = ((const u16*)mask)[i]      != 0;
    else             on = ((const uint32_t*)mask)[i] != 0;
    mb[i] = on ? -1e9f : 0.0f;
}

__global__ __launch_bounds__(256) void k_convert_bf(const void* src, u16* dst, int n, const int* flag)
{
    int i = blockIdx.x * 256 + threadIdx.x;
    if (i >= n) return;
    if (*flag == 2) dst[i] = ((const u16*)src)[i];
    else            dst[i] = f2bf(((const float*)src)[i]);
}

// ---------------------------------------------------------------------------
// Fused LDS-tiled weight transposes: 6 matrices in one launch.
// ---------------------------------------------------------------------------
struct TransArgs { const void* src[6]; u16* dst[6]; int R[6]; int C[6]; int flagidx[6]; int tstart[7]; };

__global__ __launch_bounds__(256) void k_transpose_all(TransArgs a, const int* flags)
{
    const int tb = blockIdx.x;
    int s = 0;
    while (tb >= a.tstart[s + 1]) s++;
    const int lt = tb - a.tstart[s];
    const int R = a.R[s], C = a.C[s];
    const int tilesX = C >> 5;
    const int ti = lt / tilesX, tj = lt - ti * tilesX;
    const int r0 = ti * 32, c0 = tj * 32;
    const bool isbf = (flags[a.flagidx[s]] == 2);
    const int t = threadIdx.x;
    const int j = t & 31, i0 = t >> 5;
    __shared__ u16 tile[32][33];
#pragma unroll
    for (int p = 0; p < 4; p++) {
        int r = r0 + i0 + p * 8;
        size_t idx = (size_t)r * C + c0 + j;
        u16 v = isbf ? ((const u16*)a.src[s])[idx] : f2bf(((const float*)a.src[s])[idx]);
        tile[i0 + p * 8][j] = v;
    }
    __syncthreads();
    u16* dst = a.dst[s];
#pragma unroll
    for (int p = 0; p < 4; p++) {
        int c = i0 + p * 8;
        dst[(size_t)(c0 + c) * R + r0 + j] = tile[j][c];
    }
}

// ---------------------------------------------------------------------------
// Fused param (bias/gain) converts to fp32
// ---------------------------------------------------------------------------
struct ConvArgs { const void* src[10]; int flagidx[10]; int off[10]; int n[10]; };

__global__ __launch_bounds__(256) void k_convert_params(ConvArgs a, const int* flags, float* par)
{
    int i = blockIdx.x * 256 + threadIdx.x;
    if (i >= 11264) return;
    int s = 0;
    while (s < 9 && i >= a.off[s] + a.n[s]) s++;
    int j = i - a.off[s];
    float v;
    if (flags[a.flagidx[s]] == 2) v = bf2f(((const u16*)a.src[s])[j]);
    else                          v = ((const float*)a.src[s])[j];
    par[i] = v;
}

// ---------------------------------------------------------------------------
// MFMA GEMM core with async global->LDS staging (global_load_lds width=16).
// C(M x N) = A(M x K, lda) * B(K x N) with Bt = N x K (ldb). BK=32, fp32 acc.
// LDS tiles UNPADDED (row stride 32 el = 64 B) — required by async16 layout:
// chunk c (1 KB) covers rows [c*16, c*16+16), lane l -> row c*16+l/4, col (l%4)*8.
// Requires 256 threads (4 waves). BM, BN multiples of 64.
// ---------------------------------------------------------------------------
template<int BM, int BN, int WR, int WC, int TM, int TN>
DEV void gemm_tile(const u16* __restrict__ A, int lda,
                   const u16* __restrict__ Bt, int ldb, int K,
                   u16* As, u16* Bs, f32x4 (&acc)[TM][TN])
{
    const int t = threadIdx.x;
    const int lane = t & 63;
    const int wave = t >> 6;
    const int wr = wave / WC;
    const int wc = wave % WC;
    const int m16 = lane & 15;
    const int quad = lane >> 4;
    const int lr = lane >> 2;          // 0..15: row within 16-row chunk
    const int lc8 = (lane & 3) * 8;    // col offset within 32-col tile

#pragma unroll
    for (int i = 0; i < TM; i++)
#pragma unroll
        for (int j = 0; j < TN; j++) {
            acc[i][j][0] = 0.f; acc[i][j][1] = 0.f; acc[i][j][2] = 0.f; acc[i][j][3] = 0.f;
        }

    for (int kb = 0; kb < K; kb += 32) {
#pragma unroll
        for (int i = 0; i < BM / 64; i++) {
            int chunk = wave * (BM / 64) + i;
            int r = chunk * 16 + lr;
            async16(A + (size_t)r * lda + kb + lc8, As + chunk * 512);
        }
#pragma unroll
        for (int i = 0; i < BN / 64; i++) {
            int chunk = wave * (BN / 64) + i;
            int r = chunk * 16 + lr;
            async16(Bt + (size_t)r * ldb + kb + lc8, Bs + chunk * 512);
        }
        __syncthreads();   // drains vmcnt (incl. global_load_lds) before LDS reads
        bf16x8 af[TM], bfr[TN];
#pragma unroll
        for (int i = 0; i < TM; i++)
            af[i] = *(const bf16x8*)(As + (wr * TM * 16 + i * 16 + m16) * 32 + quad * 8);
#pragma unroll
        for (int j = 0; j < TN; j++)
            bfr[j] = *(const bf16x8*)(Bs + (wc * TN * 16 + j * 16 + m16) * 32 + quad * 8);
#pragma unroll
        for (int i = 0; i < TM; i++)
#pragma unroll
            for (int j = 0; j < TN; j++)
                acc[i][j] = __builtin_amdgcn_mfma_f32_16x16x32_bf16(af[i], bfr[j], acc[i][j], 0, 0, 0);
        __syncthreads();
    }
}

template<bool RELU>
__global__ __launch_bounds__(256) void k_gemm_std(const u16* __restrict__ A, int lda,
                                                  const u16* __restrict__ Bt, int ldb,
                                                  const float* __restrict__ bias,
                                                  u16* __restrict__ C, int ldc, int K)
{
    __shared__ __align__(16) u16 As[128 * 32];
    __shared__ __align__(16) u16 Bs[128 * 32];
    const u16* Ab = A + (size_t)blockIdx.y * 128 * lda;
    const u16* Bb = Bt + (size_t)blockIdx.x * 128 * ldb;
    f32x4 acc[4][4];
    gemm_tile<128, 128, 2, 2, 4, 4>(Ab, lda, Bb, ldb, K, As, Bs, acc);

    const int t = threadIdx.x, lane = t & 63, wave = t >> 6;
    const int wr = wave >> 1, wc = wave & 1, m16 = lane & 15, quad = lane >> 4;
    const size_t rowBase = (size_t)blockIdx.y * 128 + wr * 64;
    const int colBase = blockIdx.x * 128 + wc * 64;
#pragma unroll
    for (int tm = 0; tm < 4; tm++)
#pragma unroll
        for (int tn = 0; tn < 4; tn++) {
            int col = colBase + tn * 16 + m16;
            float bv = bias ? bias[col] : 0.f;
#pragma unroll
            for (int r = 0; r < 4; r++) {
                size_t row = rowBase + tm * 16 + quad * 4 + r;
                float v = acc[tm][tn][r] + bv;
                if (RELU) v = fmaxf(v, 0.f);
                C[row * (size_t)ldc + col] = f2bf(v);
            }
        }
}

// Fused QKV: grid (4, 64, 6); z -> (g = z/3, mat = z%3). M=8192 N=512 K=512.
__global__ __launch_bounds__(256) void k_gemm_qkv(const u16* __restrict__ y_c,
                                                  const u16* __restrict__ WqT,
                                                  const u16* __restrict__ WkT,
                                                  const u16* __restrict__ WvT,
                                                  const float* __restrict__ biases,
                                                  u16* __restrict__ qp, u16* __restrict__ kp, u16* __restrict__ vp)
{
    __shared__ __align__(16) u16 As[128 * 32];
    __shared__ __align__(16) u16 Bs[128 * 32];
    const int z = blockIdx.z;
    const int mat = z % 3, g = z / 3;
    const u16* Bt = (mat == 0) ? WqT : (mat == 1) ? WkT : WvT;
    u16* out = ((mat == 0) ? qp : (mat == 1) ? kp : vp) + (size_t)g * 4194304;
    const float* bias = biases + mat * 512;
    const u16* Ab = y_c + g * 512 + (size_t)blockIdx.y * 128 * 1024;
    const u16* Bb = Bt + (size_t)blockIdx.x * 128 * 512;
    f32x4 acc[4][4];
    gemm_tile<128, 128, 2, 2, 4, 4>(Ab, 1024, Bb, 512, 512, As, Bs, acc);

    const int t = threadIdx.x, lane = t & 63, wave = t >> 6;
    const int wr = wave >> 1, wc = wave & 1, m16 = lane & 15, quad = lane >> 4;
    const size_t rowBase = (size_t)blockIdx.y * 128 + wr * 64;
    const int colBase = blockIdx.x * 128 + wc * 64;
#pragma unroll
    for (int tm = 0; tm < 4; tm++)
#pragma unroll
        for (int tn = 0; tn < 4; tn++) {
            int col = colBase + tn * 16 + m16;
            float bv = bias[col];
#pragma unroll
            for (int r = 0; r < 4; r++) {
                size_t row = rowBase + tm * 16 + quad * 4 + r;
                out[row * 512 + col] = f2bf(acc[tm][tn][r] + bv);
            }
        }
}

// ---------------------------------------------------------------------------
// Fused scores + mask + softmax -> P (bf16). Grid (4, 512).
// ---------------------------------------------------------------------------
__global__ __launch_bounds__(256) void k_attn_scores(const u16* __restrict__ qproj,
                                                     const u16* __restrict__ kproj,
                                                     const float* __restrict__ maskb,
                                                     u16* __restrict__ P)
{
    __shared__ __align__(16) u16 As[64 * 32];
    __shared__ __align__(16) u16 Bs[256 * 32];
    __shared__ float smax[64][5];
    __shared__ float ssum[64][5];
    const int rt = blockIdx.x;
    const int z = blockIdx.y;
    const int bg = z >> 4, h = z & 15, hbit = h >> 3, hlow = h & 7;
    const int b = bg & 15;
    const size_t base = (size_t)bg * 262144 + (size_t)hbit * 512 + (size_t)hlow * 64;
    const u16* A = qproj + base + (size_t)rt * 64 * 1024;
    const u16* B = kproj + base;
    f32x4 acc[4][4];
    gemm_tile<64, 256, 1, 4, 4, 4>(A, 1024, B, 1024, 64, As, Bs, acc);

    const int t = threadIdx.x, lane = t & 63, wc = t >> 6;
    const int m16 = lane & 15, quad = lane >> 4;

    float mb[4];
#pragma unroll
    for (int j = 0; j < 4; j++) mb[j] = maskb[b * 256 + wc * 64 + j * 16 + m16];
#pragma unroll
    for (int i = 0; i < 4; i++)
#pragma unroll
        for (int j = 0; j < 4; j++)
#pragma unroll
            for (int r = 0; r < 4; r++)
                acc[i][j][r] = acc[i][j][r] * 0.125f + mb[j];

#pragma unroll
    for (int i = 0; i < 4; i++)
#pragma unroll
        for (int r = 0; r < 4; r++) {
            float mm = fmaxf(fmaxf(acc[i][0][r], acc[i][1][r]), fmaxf(acc[i][2][r], acc[i][3][r]));
            mm = fmaxf(mm, __shfl_xor(mm, 1));
            mm = fmaxf(mm, __shfl_xor(mm, 2));
            mm = fmaxf(mm, __shfl_xor(mm, 4));
            mm = fmaxf(mm, __shfl_xor(mm, 8));
            if (m16 == 0) smax[i * 16 + quad * 4 + r][wc] = mm;
        }
    __syncthreads();
    float mrow[4][4];
#pragma unroll
    for (int i = 0; i < 4; i++)
#pragma unroll
        for (int r = 0; r < 4; r++) {
            int row = i * 16 + quad * 4 + r;
            mrow[i][r] = fmaxf(fmaxf(smax[row][0], smax[row][1]), fmaxf(smax[row][2], smax[row][3]));
        }
#pragma unroll
    for (int i = 0; i < 4; i++)
#pragma unroll
        for (int r = 0; r < 4; r++) {
            float s = 0.f;
#pragma unroll
            for (int j = 0; j < 4; j++) {
                float e = __expf(acc[i][j][r] - mrow[i][r]);
                acc[i][j][r] = e;
                s += e;
            }
            s += __shfl_xor(s, 1);
            s += __shfl_xor(s, 2);
            s += __shfl_xor(s, 4);
            s += __shfl_xor(s, 8);
            if (m16 == 0) ssum[i * 16 + quad * 4 + r][wc] = s;
        }
    __syncthreads();
    u16* out = P + (size_t)z * 65536 + (size_t)rt * 64 * 256;
#pragma unroll
    for (int i = 0; i < 4; i++)
#pragma unroll
        for (int r = 0; r < 4; r++) {
            int row = i * 16 + quad * 4 + r;
            float inv = 1.0f / (ssum[row][0] + ssum[row][1] + ssum[row][2] + ssum[row][3]);
#pragma unroll
            for (int j = 0; j < 4; j++) {
                int col = wc * 64 + j * 16 + m16;
                out[(size_t)row * 256 + col] = f2bf(acc[i][j][r] * inv);
            }
        }
}

// vT[(bg*16+h)*64 + dh][s] = vproj[bg][l=2s+hbit][hlow*64+dh]
__global__ __launch_bounds__(256) void k_transpose_v(const u16* __restrict__ vproj, u16* __restrict__ vT)
{
    __shared__ __align__(16) u16 tile[64 * 72];
    const int lt = blockIdx.x, hlow = blockIdx.y, bg = blockIdx.z;
    const int t = threadIdx.x;
    {
        int rl = t >> 2, c16 = (t & 3) * 16;
        const u16* src = vproj + (size_t)bg * 262144 + (size_t)(lt * 64 + rl) * 512 + hlow * 64 + c16;
        *(us8*)(tile + rl * 72 + c16)     = *(const us8*)src;
        *(us8*)(tile + rl * 72 + c16 + 8) = *(const us8*)(src + 8);
    }
    __syncthreads();
    const int lanej = t & 31, grp = t >> 5;
#pragma unroll
    for (int hbit = 0; hbit < 2; hbit++) {
        int h = hbit * 8 + hlow;
#pragma unroll
        for (int i = 0; i < 8; i++) {
            int dh = grp + i * 8;
            u16 val = tile[(2 * lanej + hbit) * 72 + dh];
            vT[(((size_t)bg * 16 + h) * 64 + dh) * 256 + lt * 32 + lanej] = val;
        }
    }
}

// ctx = P V, scatter into attedpre (B,L,H). Grid (2, 512).
__global__ __launch_bounds__(256) void k_gemm_ctx(const u16* __restrict__ P,
                                                  const u16* __restrict__ vT,
                                                  u16* __restrict__ attedpre)
{
    __shared__ __align__(16) u16 As[128 * 32];
    __shared__ __align__(16) u16 Bs[64 * 32];
    const int z = blockIdx.y;
    const u16* A = P + (size_t)z * 65536 + (size_t)blockIdx.x * 128 * 256;
    const u16* B = vT + (size_t)z * 16384;
    f32x4 acc[2][4];
    gemm_tile<128, 64, 4, 1, 2, 4>(A, 256, B, 256, 256, As, Bs, acc);

    const int t = threadIdx.x, lane = t & 63, wave = t >> 6;
    const int m16 = lane & 15, quad = lane >> 4;
    const int bg = z >> 4, h = z & 15;
    const int g = bg >> 4, b = bg & 15, hbit = h >> 3, hlow = h & 7;
    const int cBase = g * 512 + hlow * 64;
#pragma unroll
    for (int tm = 0; tm < 2; tm++)
#pragma unroll
        for (int tn = 0; tn < 4; tn++) {
            int dh = tn * 16 + m16;
#pragma unroll
            for (int r = 0; r < 4; r++) {
                int s = blockIdx.x * 128 + wave * 32 + tm * 16 + quad * 4 + r;
                int l = 2 * s + hbit;
                attedpre[((size_t)b * 512 + l) * 1024 + cBase + dh] = f2bf(acc[tm][tn][r]);
            }
        }
}

// Fused grouped FFN2: grid (8, 64). x -> (g = x>>2, xn = x&3).
__global__ __launch_bounds__(256) void k_gemm_ffn2(const u16* __restrict__ h1,
                                                   const u16* __restrict__ W2T,
                                                   const float* __restrict__ b2,
                                                   u16* __restrict__ out)
{
    __shared__ __align__(16) u16 As[128 * 32];
    __shared__ __align__(16) u16 Bs[128 * 32];
    const int xi = blockIdx.x;
    const int g = xi >> 2, xn = xi & 3;
    const u16* Ab = h1 + (size_t)blockIdx.y * 128 * 4096 + g * 2048;
    const u16* Bb = W2T + (size_t)xn * 128 * 2048;
    f32x4 acc[4][4];
    gemm_tile<128, 128, 2, 2, 4, 4>(Ab, 4096, Bb, 2048, 2048, As, Bs, acc);

    const int t = threadIdx.x, lane = t & 63, wave = t >> 6;
    const int wr = wave >> 1, wc = wave & 1, m16 = lane & 15, quad = lane >> 4;
    const size_t rowBase = (size_t)blockIdx.y * 128 + wr * 64;
    const int colg = xn * 128 + wc * 64;
#pragma unroll
    for (int tm = 0; tm < 4; tm++)
#pragma unroll
        for (int tn = 0; tn < 4; tn++) {
            int cg = colg + tn * 16 + m16;
            float bv = b2[cg];
#pragma unroll
            for (int r = 0; r < 4; r++) {
                size_t row = rowBase + tm * 16 + quad * 4 + r;
                out[row * 1024 + g * 512 + cg] = f2bf(acc[tm][tn][r] + bv);
            }
        }
}

// out = LN(x1 + x2) * gamma + beta over D=1024; one block per row.
template<int FINAL>
__global__ __launch_bounds__(256) void k_ln(const u16* __restrict__ x1, const u16* __restrict__ x2,
                                            const float* __restrict__ gamma, const float* __restrict__ beta,
                                            void* __restrict__ outv, const int* __restrict__ yflag)
{
    const size_t row = blockIdx.x;
    const int t = threadIdx.x;
    us4 a = *(const us4*)(x1 + row * 1024 + t * 4);
    us4 b = *(const us4*)(x2 + row * 1024 + t * 4);
    float v[4]; float s = 0.f, s2 = 0.f;
#pragma unroll
    for (int i = 0; i < 4; i++) { v[i] = bf2f(a[i]) + bf2f(b[i]); s += v[i]; s2 += v[i] * v[i]; }
#pragma unroll
    for (int off = 32; off > 0; off >>= 1) { s += __shfl_xor(s, off); s2 += __shfl_xor(s2, off); }
    __shared__ float red[8];
    const int lane = t & 63, wave = t >> 6;
    if (lane == 0) { red[wave] = s; red[wave + 4] = s2; }
    __syncthreads();
    s = red[0] + red[1] + red[2] + red[3];
    s2 = red[4] + red[5] + red[6] + red[7];
    float mean = s * (1.0f / 1024.0f);
    float var = fmaxf(s2 * (1.0f / 1024.0f) - mean * mean, 0.0f);
    float rs = rsqrtf(var + 1e-6f);
    float o[4];
#pragma unroll
    for (int i = 0; i < 4; i++) {
        int c = t * 4 + i;
        o[i] = (v[i] - mean) * rs * gamma[c] + beta[c];
    }
    bool f32out = FINAL && yflag && (*yflag == 3);
    if (f32out) {
        float* out = (float*)outv;
#pragma unroll
        for (int i = 0; i < 4; i++) out[row * 1024 + t * 4 + i] = o[i];
    } else {
        u16* out = (u16*)outv;
        us4 ov;
#pragma unroll
        for (int i = 0; i < 4; i++) ov[i] = f2bf(o[i]);
        *(us4*)(out + row * 1024 + t * 4) = ov;
    }
}

// ---------------------------------------------------------------------------
extern "C" void kernel_launch(void* const* d_in, const int* in_sizes, int n_in,
                              void* d_out, int out_size, void* d_ws, size_t ws_size,
                              hipStream_t stream)
{
    (void)in_sizes; (void)n_in; (void)out_size; (void)ws_size;
    const void* y    = d_in[0];
    const void* mask = d_in[1];
    const void* Wv = d_in[2];  const void* bv = d_in[3];
    const void* Wk = d_in[4];  const void* bk = d_in[5];
    const void* Wq = d_in[6];  const void* bq = d_in[7];
    const void* Wm = d_in[8];  const void* bm = d_in[9];
    const void* W1 = d_in[10]; const void* b1 = d_in[11];
    const void* W2 = d_in[12]; const void* b2 = d_in[13];
    const void* g1 = d_in[14]; const void* be1 = d_in[15];
    const void* g2 = d_in[16]; const void* be2 = d_in[17];

    char* ws = (char*)d_ws;
    size_t off = 0;
    auto alloc = [&](size_t bytes) { void* p = ws + off; off = (off + bytes + 255) & ~(size_t)255; return p; };

    int*   flags = (int*)alloc(32 * 4);
    float* maskb = (float*)alloc(16 * 256 * 4);
    float* par   = (float*)alloc(11264 * 4);
    u16* WqT  = (u16*)alloc((size_t)262144 * 2);
    u16* WkT  = (u16*)alloc((size_t)262144 * 2);
    u16* WvT  = (u16*)alloc((size_t)262144 * 2);
    u16* WmT  = (u16*)alloc((size_t)1048576 * 2);
    u16* W1T  = (u16*)alloc((size_t)4194304 * 2);
    u16* W2T  = (u16*)alloc((size_t)1048576 * 2);
    u16* y_c  = (u16*)alloc((size_t)8388608 * 2);
    u16* slotA = (u16*)alloc((size_t)8388608 * 2);   // qproj -> mergeout
    u16* slotB = (u16*)alloc((size_t)8388608 * 2);   // kproj -> y1
    u16* slotC = (u16*)alloc((size_t)8388608 * 2);   // vT -> ffout
    u16* slotD = (u16*)alloc((size_t)8388608 * 2);   // vproj -> attedpre
    u16* Pbig  = (u16*)alloc((size_t)33554432 * 2);  // P (64 MB) -> h1 (32 MB)

    float* p_bm  = par + 1536;
    float* p_b1  = par + 2560;
    float* p_b2  = par + 6656;
    float* p_g1  = par + 7168;
    float* p_be1 = par + 8192;
    float* p_g2  = par + 9216;
    float* p_be2 = par + 10240;

    DetectArgs da;
    {
        const void* srcs[18] = {y, mask, Wv, bv, Wk, bk, Wq, bq, Wm, bm, W1, b1, W2, b2, g1, be1, g2, be2};
        const int   nele[18] = {8388608, 4096, 262144, 512, 262144, 512, 262144, 512, 1048576, 1024,
                                4194304, 4096, 1048576, 512, 1024, 1024, 1024, 1024};
        for (int i = 0; i < 18; i++) { da.p[i] = srcs[i]; da.nw[i] = nele[i] < 4096 ? nele[i] : 4096; }
    }
    k_detect_all<<<18, 256, 0, stream>>>(da, flags);

    k_expand_mask<<<16, 256, 0, stream>>>(mask, flags + 1, maskb);
    k_convert_bf<<<32768, 256, 0, stream>>>(y, y_c, 8388608, flags + 0);

    TransArgs ta;
    {
        const void* s6[6] = {Wq, Wk, Wv, Wm, W1, W2};
        u16* d6[6] = {WqT, WkT, WvT, WmT, W1T, W2T};
        int R6[6] = {512, 512, 512, 1024, 1024, 2048};
        int C6[6] = {512, 512, 512, 1024, 4096, 512};
        int f6[6] = {6, 4, 2, 8, 10, 12};
        int ts[7] = {0, 256, 512, 768, 1792, 5888, 6912};
        for (int i = 0; i < 6; i++) { ta.src[i] = s6[i]; ta.dst[i] = d6[i]; ta.R[i] = R6[i]; ta.C[i] = C6[i]; ta.flagidx[i] = f6[i]; }
        for (int i = 0; i < 7; i++) ta.tstart[i] = ts[i];
    }
    k_transpose_all<<<6912, 256, 0, stream>>>(ta, flags);

    ConvArgs ca;
    {
        const void* s10[10] = {bq, bk, bv, bm, b1, b2, g1, be1, g2, be2};
        int f10[10] = {7, 5, 3, 9, 11, 13, 14, 15, 16, 17};
        int o10[10] = {0, 512, 1024, 1536, 2560, 6656, 7168, 8192, 9216, 10240};
        int n10[10] = {512, 512, 512, 1024, 4096, 512, 1024, 1024, 1024, 1024};
        for (int i = 0; i < 10; i++) { ca.src[i] = s10[i]; ca.flagidx[i] = f10[i]; ca.off[i] = o10[i]; ca.n[i] = n10[i]; }
    }
    k_convert_params<<<44, 256, 0, stream>>>(ca, flags, par);

    u16* qproj = slotA;
    u16* kproj = slotB;
    u16* vT    = slotC;
    u16* vproj = slotD;

    k_gemm_qkv<<<dim3(4, 64, 6), 256, 0, stream>>>(y_c, WqT, WkT, WvT, par, qproj, kproj, vproj);
    k_transpose_v<<<dim3(8, 8, 32), 256, 0, stream>>>(vproj, vT);

    u16* P = Pbig;
    k_attn_scores<<<dim3(4, 512), 256, 0, stream>>>(qproj, kproj, maskb, P);

    u16* attedpre = slotD;   // vproj dead
    k_gemm_ctx<<<dim3(2, 512), 256, 0, stream>>>(P, vT, attedpre);

    u16* mergeout = slotA;   // qproj dead
    k_gemm_std<false><<<dim3(8, 64), 256, 0, stream>>>(attedpre, 1024, WmT, 1024, p_bm, mergeout, 1024, 1024);

    u16* y1 = slotB;         // kproj dead
    k_ln<0><<<8192, 256, 0, stream>>>(y_c, mergeout, p_g1, p_be1, y1, nullptr);

    u16* h1 = Pbig;          // P dead after ctx
    k_gemm_std<true><<<dim3(32, 64), 256, 0, stream>>>(y1, 1024, W1T, 1024, p_b1, h1, 4096, 1024);

    u16* ffout = slotC;      // vT dead
    k_gemm_ffn2<<<dim3(8, 64), 256, 0, stream>>>(h1, W2T, p_b2, ffout);

    k_ln<1><<<8192, 256, 0, stream>>>(y1, ffout, p_g2, p_be2, d_out, flags + 0);
}

// Round 7
// 468.875 us; speedup vs baseline: 2.6063x; 1.0489x over previous
//
#include <hip/hip_runtime.h>
#include <stdint.h>

typedef unsigned short u16;
using us8   = __attribute__((ext_vector_type(8))) unsigned short;
using us4   = __attribute__((ext_vector_type(4))) unsigned short;
using bf16x8 = __attribute__((ext_vector_type(8))) __bf16;
using f32x4 = __attribute__((ext_vector_type(4))) float;

#define DEV static __device__ __forceinline__

DEV float bf2f(u16 u) { union { uint32_t i; float f; } v; v.i = (uint32_t)u << 16; return v.f; }
DEV u16 f2bf(float f) {
    union { float f; uint32_t i; } v; v.f = f;
    uint32_t u = v.i;
    return (u16)((u + 0x7FFFu + ((u >> 16) & 1u)) >> 16);
}

// async global->LDS 16B copy: lane l writes LDS at (uniform base) + l*16B.
DEV void async16(const u16* g, u16* ldsbase)
{
    __builtin_amdgcn_global_load_lds((const __attribute__((address_space(1))) void*)g,
                                     (__attribute__((address_space(3))) void*)ldsbase, 16, 0, 0);
}

// ---------------------------------------------------------------------------
// Fused dtype detection: 18 blocks, one per input tensor.
// ---------------------------------------------------------------------------
struct DetectArgs { const void* p[18]; int nw[18]; };

__global__ __launch_bounds__(256) void k_detect_all(DetectArgs a, int* flags)
{
    const int b = blockIdx.x;
    const int t = threadIdx.x;
    __shared__ int cnt[4];
    if (t < 4) cnt[t] = 0;
    __syncthreads();
    if (b == 1) {
        const uint8_t* m = (const uint8_t*)a.p[1];
        int c0 = 0, c1 = 0, c2 = 0, c3 = 0;
        for (int i = t; i < 4096; i += 256) {
            uint8_t v = m[i];
            int mod = i & 3;
            if (v == 0x3F && mod == 1) c0++;
            if (v == 0x3F && mod == 3) c1++;
            if (v == 1 && mod != 0) c2++;
            if (v == 1 && mod == 0) c3++;
        }
        atomicAdd(&cnt[0], c0); atomicAdd(&cnt[1], c1); atomicAdd(&cnt[2], c2); atomicAdd(&cnt[3], c3);
        __syncthreads();
        if (t == 0) {
            int mf;
            if (cnt[0] > 0) mf = 2;
            else if (cnt[1] > 0) mf = 3;
            else if (cnt[2] > 0) mf = 0;
            else if (cnt[3] > 0) mf = 1;
            else mf = 0;
            flags[1] = mf;
        }
    } else {
        const u16* p = (const u16*)a.p[b];
        int nw = a.nw[b];
        int nze = 0, pe = 0, nzo = 0;
        for (int i = t; i < nw; i += 256) {
            u16 w = p[i];
            if (w == 0) continue;
            int e = (w >> 7) & 0xFF;
            bool pl = (e >= 90 && e <= 140);
            if ((i & 1) == 0) { nze++; if (pl) pe++; }
            else nzo++;
        }
        atomicAdd(&cnt[0], nze); atomicAdd(&cnt[1], pe); atomicAdd(&cnt[2], nzo);
        __syncthreads();
        if (t == 0) {
            int f;
            if (cnt[0] > 0)      f = (cnt[1] * 10 >= cnt[0] * 6) ? 2 : 3;
            else if (cnt[2] > 0) f = 3;
            else                 f = 2;
            flags[b] = f;
        }
    }
}

__global__ __launch_bounds__(256) void k_expand_mask(const void* mask, const int* flag, float* mb)
{
    int i = blockIdx.x * 256 + threadIdx.x;
    if (i >= 4096) return;
    int f = *flag;
    bool on;
    if (f == 0)      on = ((const uint8_t*)mask)[i]  != 0;
    else if (f == 1) on = ((const int*)mask)[i]      != 0;
    else if (f == 2) on = ((const u16*)mask)[i]      != 0;
    else             on = ((const uint32_t*)mask)[i] != 0;
    mb[i] = on ? -1e9f : 0.0f;
}

__global__ __launch_bounds__(256) void k_convert_bf(const void* src, u16* dst, int n, const int* flag)
{
    int i = blockIdx.x * 256 + threadIdx.x;
    if (i >= n) return;
    if (*flag == 2) dst[i] = ((const u16*)src)[i];
    else            dst[i] = f2bf(((const float*)src)[i]);
}

// ---------------------------------------------------------------------------
// Fused LDS-tiled weight transposes
// ---------------------------------------------------------------------------
struct TransArgs { const void* src[6]; u16* dst[6]; int R[6]; int C[6]; int flagidx[6]; int tstart[7]; };

__global__ __launch_bounds__(256) void k_transpose_all(TransArgs a, const int* flags)
{
    const int tb = blockIdx.x;
    int s = 0;
    while (tb >= a.tstart[s + 1]) s++;
    const int lt = tb - a.tstart[s];
    const int R = a.R[s], C = a.C[s];
    const int tilesX = C >> 5;
    const int ti = lt / tilesX, tj = lt - ti * tilesX;
    const int r0 = ti * 32, c0 = tj * 32;
    const bool isbf = (flags[a.flagidx[s]] == 2);
    const int t = threadIdx.x;
    const int j = t & 31, i0 = t >> 5;
    __shared__ u16 tile[32][33];
#pragma unroll
    for (int p = 0; p < 4; p++) {
        int r = r0 + i0 + p * 8;
        size_t idx = (size_t)r * C + c0 + j;
        u16 v = isbf ? ((const u16*)a.src[s])[idx] : f2bf(((const float*)a.src[s])[idx]);
        tile[i0 + p * 8][j] = v;
    }
    __syncthreads();
    u16* dst = a.dst[s];
#pragma unroll
    for (int p = 0; p < 4; p++) {
        int c = i0 + p * 8;
        dst[(size_t)(c0 + c) * R + r0 + j] = tile[j][c];
    }
}

// ---------------------------------------------------------------------------
// Fused param converts
// ---------------------------------------------------------------------------
struct ConvArgs { const void* src[10]; int flagidx[10]; int off[10]; int n[10]; };

__global__ __launch_bounds__(256) void k_convert_params(ConvArgs a, const int* flags, float* par)
{
    int i = blockIdx.x * 256 + threadIdx.x;
    if (i >= 11264) return;
    int s = 0;
    while (s < 9 && i >= a.off[s] + a.n[s]) s++;
    int j = i - a.off[s];
    float v;
    if (flags[a.flagidx[s]] == 2) v = bf2f(((const u16*)a.src[s])[j]);
    else                          v = ((const float*)a.src[s])[j];
    par[i] = v;
}

// ---------------------------------------------------------------------------
// MFMA GEMM core, BK=64, async global->LDS staging with XOR-swizzled layout.
// C(M x N) = A(M x K, lda) * Bt(N x K, ldb)^T. fp32 accum. 256 threads.
// LDS tile: BM(/BN) rows x 64 cols bf16, rows stride 64 el (128 B), row r's
// 8-col chunk j stored at slot j^(r&7)  ->  fragment ds_read_b128 hits all 32
// banks with 2 lanes/bank (free).  Staged in 1 KB chunks of 8 rows: lane l
// loads row chunk*8 + l/8, col-chunk (l&7)^(l>>3).
// K must be a multiple of 64. BM, BN multiples of 32.
// ---------------------------------------------------------------------------
template<int BM, int BN, int WR, int WC, int TM, int TN>
DEV void gemm_tile(const u16* __restrict__ A, int lda,
                   const u16* __restrict__ Bt, int ldb, int K,
                   u16* As, u16* Bs, f32x4 (&acc)[TM][TN])
{
    const int t = threadIdx.x;
    const int lane = t & 63;
    const int wave = t >> 6;
    const int wr = wave / WC;
    const int wc = wave % WC;
    const int m16 = lane & 15;
    const int quad = lane >> 4;
    const int lr8 = lane >> 3;                 // 0..7 row within 8-row chunk
    const int lsw = (((lane & 7) ^ lr8) << 3); // swizzled col offset (elements)

#pragma unroll
    for (int i = 0; i < TM; i++)
#pragma unroll
        for (int j = 0; j < TN; j++) {
            acc[i][j][0] = 0.f; acc[i][j][1] = 0.f; acc[i][j][2] = 0.f; acc[i][j][3] = 0.f;
        }

    for (int kb = 0; kb < K; kb += 64) {
#pragma unroll
        for (int i = 0; i < BM / 32; i++) {
            int chunk = wave * (BM / 32) + i;
            int r = chunk * 8 + lr8;
            async16(A + (size_t)r * lda + kb + lsw, As + chunk * 512);
        }
#pragma unroll
        for (int i = 0; i < BN / 32; i++) {
            int chunk = wave * (BN / 32) + i;
            int r = chunk * 8 + lr8;
            async16(Bt + (size_t)r * ldb + kb + lsw, Bs + chunk * 512);
        }
        __syncthreads();   // drains vmcnt (incl. global_load_lds) before LDS reads
#pragma unroll
        for (int ks = 0; ks < 2; ks++) {
            bf16x8 af[TM], bfr[TN];
#pragma unroll
            for (int i = 0; i < TM; i++) {
                int row = wr * TM * 16 + i * 16 + m16;
                int jq = ks * 4 + quad;
                af[i] = *(const bf16x8*)(As + row * 64 + ((jq ^ (row & 7)) << 3));
            }
#pragma unroll
            for (int j = 0; j < TN; j++) {
                int row = wc * TN * 16 + j * 16 + m16;
                int jq = ks * 4 + quad;
                bfr[j] = *(const bf16x8*)(Bs + row * 64 + ((jq ^ (row & 7)) << 3));
            }
#pragma unroll
            for (int i = 0; i < TM; i++)
#pragma unroll
                for (int j = 0; j < TN; j++)
                    acc[i][j] = __builtin_amdgcn_mfma_f32_16x16x32_bf16(af[i], bfr[j], acc[i][j], 0, 0, 0);
        }
        __syncthreads();
    }
}

template<bool RELU>
__global__ __launch_bounds__(256) void k_gemm_std(const u16* __restrict__ A, int lda,
                                                  const u16* __restrict__ Bt, int ldb,
                                                  const float* __restrict__ bias,
                                                  u16* __restrict__ C, int ldc, int K)
{
    __shared__ __align__(16) u16 As[128 * 64];
    __shared__ __align__(16) u16 Bs[128 * 64];
    const u16* Ab = A + (size_t)blockIdx.y * 128 * lda;
    const u16* Bb = Bt + (size_t)blockIdx.x * 128 * ldb;
    f32x4 acc[4][4];
    gemm_tile<128, 128, 2, 2, 4, 4>(Ab, lda, Bb, ldb, K, As, Bs, acc);

    const int t = threadIdx.x, lane = t & 63, wave = t >> 6;
    const int wr = wave >> 1, wc = wave & 1, m16 = lane & 15, quad = lane >> 4;
    const size_t rowBase = (size_t)blockIdx.y * 128 + wr * 64;
    const int colBase = blockIdx.x * 128 + wc * 64;
#pragma unroll
    for (int tm = 0; tm < 4; tm++)
#pragma unroll
        for (int tn = 0; tn < 4; tn++) {
            int col = colBase + tn * 16 + m16;
            float bv = bias ? bias[col] : 0.f;
#pragma unroll
            for (int r = 0; r < 4; r++) {
                size_t row = rowBase + tm * 16 + quad * 4 + r;
                float v = acc[tm][tn][r] + bv;
                if (RELU) v = fmaxf(v, 0.f);
                C[row * (size_t)ldc + col] = f2bf(v);
            }
        }
}

// Fused QKV: grid (4, 64, 6); z -> (g = z/3, mat = z%3). M=8192 N=512 K=512.
__global__ __launch_bounds__(256) void k_gemm_qkv(const u16* __restrict__ y_c,
                                                  const u16* __restrict__ WqT,
                                                  const u16* __restrict__ WkT,
                                                  const u16* __restrict__ WvT,
                                                  const float* __restrict__ biases,
                                                  u16* __restrict__ qp, u16* __restrict__ kp, u16* __restrict__ vp)
{
    __shared__ __align__(16) u16 As[128 * 64];
    __shared__ __align__(16) u16 Bs[128 * 64];
    const int z = blockIdx.z;
    const int mat = z % 3, g = z / 3;
    const u16* Bt = (mat == 0) ? WqT : (mat == 1) ? WkT : WvT;
    u16* out = ((mat == 0) ? qp : (mat == 1) ? kp : vp) + (size_t)g * 4194304;
    const float* bias = biases + mat * 512;
    const u16* Ab = y_c + g * 512 + (size_t)blockIdx.y * 128 * 1024;
    const u16* Bb = Bt + (size_t)blockIdx.x * 128 * 512;
    f32x4 acc[4][4];
    gemm_tile<128, 128, 2, 2, 4, 4>(Ab, 1024, Bb, 512, 512, As, Bs, acc);

    const int t = threadIdx.x, lane = t & 63, wave = t >> 6;
    const int wr = wave >> 1, wc = wave & 1, m16 = lane & 15, quad = lane >> 4;
    const size_t rowBase = (size_t)blockIdx.y * 128 + wr * 64;
    const int colBase = blockIdx.x * 128 + wc * 64;
#pragma unroll
    for (int tm = 0; tm < 4; tm++)
#pragma unroll
        for (int tn = 0; tn < 4; tn++) {
            int col = colBase + tn * 16 + m16;
            float bv = bias[col];
#pragma unroll
            for (int r = 0; r < 4; r++) {
                size_t row = rowBase + tm * 16 + quad * 4 + r;
                out[row * 512 + col] = f2bf(acc[tm][tn][r] + bv);
            }
        }
}

// ---------------------------------------------------------------------------
// Fused scores + mask + softmax -> P (bf16). Grid (4, 512). K=64 (one iter).
// ---------------------------------------------------------------------------
__global__ __launch_bounds__(256) void k_attn_scores(const u16* __restrict__ qproj,
                                                     const u16* __restrict__ kproj,
                                                     const float* __restrict__ maskb,
                                                     u16* __restrict__ P)
{
    __shared__ __align__(16) u16 As[64 * 64];
    __shared__ __align__(16) u16 Bs[256 * 64];
    __shared__ float smax[64][5];
    __shared__ float ssum[64][5];
    const int rt = blockIdx.x;
    const int z = blockIdx.y;
    const int bg = z >> 4, h = z & 15, hbit = h >> 3, hlow = h & 7;
    const int b = bg & 15;
    const size_t base = (size_t)bg * 262144 + (size_t)hbit * 512 + (size_t)hlow * 64;
    const u16* A = qproj + base + (size_t)rt * 64 * 1024;
    const u16* B = kproj + base;
    f32x4 acc[4][4];
    gemm_tile<64, 256, 1, 4, 4, 4>(A, 1024, B, 1024, 64, As, Bs, acc);

    const int t = threadIdx.x, lane = t & 63, wc = t >> 6;
    const int m16 = lane & 15, quad = lane >> 4;

    float mb[4];
#pragma unroll
    for (int j = 0; j < 4; j++) mb[j] = maskb[b * 256 + wc * 64 + j * 16 + m16];
#pragma unroll
    for (int i = 0; i < 4; i++)
#pragma unroll
        for (int j = 0; j < 4; j++)
#pragma unroll
            for (int r = 0; r < 4; r++)
                acc[i][j][r] = acc[i][j][r] * 0.125f + mb[j];

#pragma unroll
    for (int i = 0; i < 4; i++)
#pragma unroll
        for (int r = 0; r < 4; r++) {
            float mm = fmaxf(fmaxf(acc[i][0][r], acc[i][1][r]), fmaxf(acc[i][2][r], acc[i][3][r]));
            mm = fmaxf(mm, __shfl_xor(mm, 1));
            mm = fmaxf(mm, __shfl_xor(mm, 2));
            mm = fmaxf(mm, __shfl_xor(mm, 4));
            mm = fmaxf(mm, __shfl_xor(mm, 8));
            if (m16 == 0) smax[i * 16 + quad * 4 + r][wc] = mm;
        }
    __syncthreads();
    float mrow[4][4];
#pragma unroll
    for (int i = 0; i < 4; i++)
#pragma unroll
        for (int r = 0; r < 4; r++) {
            int row = i * 16 + quad * 4 + r;
            mrow[i][r] = fmaxf(fmaxf(smax[row][0], smax[row][1]), fmaxf(smax[row][2], smax[row][3]));
        }
#pragma unroll
    for (int i = 0; i < 4; i++)
#pragma unroll
        for (int r = 0; r < 4; r++) {
            float s = 0.f;
#pragma unroll
            for (int j = 0; j < 4; j++) {
                float e = __expf(acc[i][j][r] - mrow[i][r]);
                acc[i][j][r] = e;
                s += e;
            }
            s += __shfl_xor(s, 1);
            s += __shfl_xor(s, 2);
            s += __shfl_xor(s, 4);
            s += __shfl_xor(s, 8);
            if (m16 == 0) ssum[i * 16 + quad * 4 + r][wc] = s;
        }
    __syncthreads();
    u16* out = P + (size_t)z * 65536 + (size_t)rt * 64 * 256;
#pragma unroll
    for (int i = 0; i < 4; i++)
#pragma unroll
        for (int r = 0; r < 4; r++) {
            int row = i * 16 + quad * 4 + r;
            float inv = 1.0f / (ssum[row][0] + ssum[row][1] + ssum[row][2] + ssum[row][3]);
#pragma unroll
            for (int j = 0; j < 4; j++) {
                int col = wc * 64 + j * 16 + m16;
                out[(size_t)row * 256 + col] = f2bf(acc[i][j][r] * inv);
            }
        }
}

// vT[(bg*16+h)*64 + dh][s] = vproj[bg][l=2s+hbit][hlow*64+dh]
__global__ __launch_bounds__(256) void k_transpose_v(const u16* __restrict__ vproj, u16* __restrict__ vT)
{
    __shared__ __align__(16) u16 tile[64 * 72];
    const int lt = blockIdx.x, hlow = blockIdx.y, bg = blockIdx.z;
    const int t = threadIdx.x;
    {
        int rl = t >> 2, c16 = (t & 3) * 16;
        const u16* src = vproj + (size_t)bg * 262144 + (size_t)(lt * 64 + rl) * 512 + hlow * 64 + c16;
        *(us8*)(tile + rl * 72 + c16)     = *(const us8*)src;
        *(us8*)(tile + rl * 72 + c16 + 8) = *(const us8*)(src + 8);
    }
    __syncthreads();
    const int lanej = t & 31, grp = t >> 5;
#pragma unroll
    for (int hbit = 0; hbit < 2; hbit++) {
        int h = hbit * 8 + hlow;
#pragma unroll
        for (int i = 0; i < 8; i++) {
            int dh = grp + i * 8;
            u16 val = tile[(2 * lanej + hbit) * 72 + dh];
            vT[(((size_t)bg * 16 + h) * 64 + dh) * 256 + lt * 32 + lanej] = val;
        }
    }
}

// ctx = P V, scatter into attedpre (B,L,H). Grid (2, 512). K=256.
__global__ __launch_bounds__(256) void k_gemm_ctx(const u16* __restrict__ P,
                                                  const u16* __restrict__ vT,
                                                  u16* __restrict__ attedpre)
{
    __shared__ __align__(16) u16 As[128 * 64];
    __shared__ __align__(16) u16 Bs[64 * 64];
    const int z = blockIdx.y;
    const u16* A = P + (size_t)z * 65536 + (size_t)blockIdx.x * 128 * 256;
    const u16* B = vT + (size_t)z * 16384;
    f32x4 acc[2][4];
    gemm_tile<128, 64, 4, 1, 2, 4>(A, 256, B, 256, 256, As, Bs, acc);

    const int t = threadIdx.x, lane = t & 63, wave = t >> 6;
    const int m16 = lane & 15, quad = lane >> 4;
    const int bg = z >> 4, h = z & 15;
    const int g = bg >> 4, b = bg & 15, hbit = h >> 3, hlow = h & 7;
    const int cBase = g * 512 + hlow * 64;
#pragma unroll
    for (int tm = 0; tm < 2; tm++)
#pragma unroll
        for (int tn = 0; tn < 4; tn++) {
            int dh = tn * 16 + m16;
#pragma unroll
            for (int r = 0; r < 4; r++) {
                int s = blockIdx.x * 128 + wave * 32 + tm * 16 + quad * 4 + r;
                int l = 2 * s + hbit;
                attedpre[((size_t)b * 512 + l) * 1024 + cBase + dh] = f2bf(acc[tm][tn][r]);
            }
        }
}

// Fused grouped FFN2: grid (8, 64). x -> (g = x>>2, xn = x&3).
__global__ __launch_bounds__(256) void k_gemm_ffn2(const u16* __restrict__ h1,
                                                   const u16* __restrict__ W2T,
                                                   const float* __restrict__ b2,
                                                   u16* __restrict__ out)
{
    __shared__ __align__(16) u16 As[128 * 64];
    __shared__ __align__(16) u16 Bs[128 * 64];
    const int xi = blockIdx.x;
    const int g = xi >> 2, xn = xi & 3;
    const u16* Ab = h1 + (size_t)blockIdx.y * 128 * 4096 + g * 2048;
    const u16* Bb = W2T + (size_t)xn * 128 * 2048;
    f32x4 acc[4][4];
    gemm_tile<128, 128, 2, 2, 4, 4>(Ab, 4096, Bb, 2048, 2048, As, Bs, acc);

    const int t = threadIdx.x, lane = t & 63, wave = t >> 6;
    const int wr = wave >> 1, wc = wave & 1, m16 = lane & 15, quad = lane >> 4;
    const size_t rowBase = (size_t)blockIdx.y * 128 + wr * 64;
    const int colg = xn * 128 + wc * 64;
#pragma unroll
    for (int tm = 0; tm < 4; tm++)
#pragma unroll
        for (int tn = 0; tn < 4; tn++) {
            int cg = colg + tn * 16 + m16;
            float bv = b2[cg];
#pragma unroll
            for (int r = 0; r < 4; r++) {
                size_t row = rowBase + tm * 16 + quad * 4 + r;
                out[row * 1024 + g * 512 + cg] = f2bf(acc[tm][tn][r] + bv);
            }
        }
}

// out = LN(x1 + x2) * gamma + beta over D=1024; one block per row.
template<int FINAL>
__global__ __launch_bounds__(256) void k_ln(const u16* __restrict__ x1, const u16* __restrict__ x2,
                                            const float* __restrict__ gamma, const float* __restrict__ beta,
                                            void* __restrict__ outv, const int* __restrict__ yflag)
{
    const size_t row = blockIdx.x;
    const int t = threadIdx.x;
    us4 a = *(const us4*)(x1 + row * 1024 + t * 4);
    us4 b = *(const us4*)(x2 + row * 1024 + t * 4);
    float v[4]; float s = 0.f, s2 = 0.f;
#pragma unroll
    for (int i = 0; i < 4; i++) { v[i] = bf2f(a[i]) + bf2f(b[i]); s += v[i]; s2 += v[i] * v[i]; }
#pragma unroll
    for (int off = 32; off > 0; off >>= 1) { s += __shfl_xor(s, off); s2 += __shfl_xor(s2, off); }
    __shared__ float red[8];
    const int lane = t & 63, wave = t >> 6;
    if (lane == 0) { red[wave] = s; red[wave + 4] = s2; }
    __syncthreads();
    s = red[0] + red[1] + red[2] + red[3];
    s2 = red[4] + red[5] + red[6] + red[7];
    float mean = s * (1.0f / 1024.0f);
    float var = fmaxf(s2 * (1.0f / 1024.0f) - mean * mean, 0.0f);
    float rs = rsqrtf(var + 1e-6f);
    float o[4];
#pragma unroll
    for (int i = 0; i < 4; i++) {
        int c = t * 4 + i;
        o[i] = (v[i] - mean) * rs * gamma[c] + beta[c];
    }
    bool f32out = FINAL && yflag && (*yflag == 3);
    if (f32out) {
        float* out = (float*)outv;
#pragma unroll
        for (int i = 0; i < 4; i++) out[row * 1024 + t * 4 + i] = o[i];
    } else {
        u16* out = (u16*)outv;
        us4 ov;
#pragma unroll
        for (int i = 0; i < 4; i++) ov[i] = f2bf(o[i]);
        *(us4*)(out + row * 1024 + t * 4) = ov;
    }
}

// ---------------------------------------------------------------------------
extern "C" void kernel_launch(void* const* d_in, const int* in_sizes, int n_in,
                              void* d_out, int out_size, void* d_ws, size_t ws_size,
                              hipStream_t stream)
{
    (void)in_sizes; (void)n_in; (void)out_size; (void)ws_size;
    const void* y    = d_in[0];
    const void* mask = d_in[1];
    const void* Wv = d_in[2];  const void* bv = d_in[3];
    const void* Wk = d_in[4];  const void* bk = d_in[5];
    const void* Wq = d_in[6];  const void* bq = d_in[7];
    const void* Wm = d_in[8];  const void* bm = d_in[9];
    const void* W1 = d_in[10]; const void* b1 = d_in[11];
    const void* W2 = d_in[12]; const void* b2 = d_in[13];
    const void* g1 = d_in[14]; const void* be1 = d_in[15];
    const void* g2 = d_in[16]; const void* be2 = d_in[17];

    char* ws = (char*)d_ws;
    size_t off = 0;
    auto alloc = [&](size_t bytes) { void* p = ws + off; off = (off + bytes + 255) & ~(size_t)255; return p; };

    int*   flags = (int*)alloc(32 * 4);
    float* maskb = (float*)alloc(16 * 256 * 4);
    float* par   = (float*)alloc(11264 * 4);
    u16* WqT  = (u16*)alloc((size_t)262144 * 2);
    u16* WkT  = (u16*)alloc((size_t)262144 * 2);
    u16* WvT  = (u16*)alloc((size_t)262144 * 2);
    u16* WmT  = (u16*)alloc((size_t)1048576 * 2);
    u16* W1T  = (u16*)alloc((size_t)4194304 * 2);
    u16* W2T  = (u16*)alloc((size_t)1048576 * 2);
    u16* y_c  = (u16*)alloc((size_t)8388608 * 2);
    u16* slotA = (u16*)alloc((size_t)8388608 * 2);   // qproj -> mergeout
    u16* slotB = (u16*)alloc((size_t)8388608 * 2);   // kproj -> y1
    u16* slotC = (u16*)alloc((size_t)8388608 * 2);   // vT -> ffout
    u16* slotD = (u16*)alloc((size_t)8388608 * 2);   // vproj -> attedpre
    u16* Pbig  = (u16*)alloc((size_t)33554432 * 2);  // P (64 MB) -> h1 (32 MB)

    float* p_bm  = par + 1536;
    float* p_b1  = par + 2560;
    float* p_b2  = par + 6656;
    float* p_g1  = par + 7168;
    float* p_be1 = par + 8192;
    float* p_g2  = par + 9216;
    float* p_be2 = par + 10240;

    DetectArgs da;
    {
        const void* srcs[18] = {y, mask, Wv, bv, Wk, bk, Wq, bq, Wm, bm, W1, b1, W2, b2, g1, be1, g2, be2};
        const int   nele[18] = {8388608, 4096, 262144, 512, 262144, 512, 262144, 512, 1048576, 1024,
                                4194304, 4096, 1048576, 512, 1024, 1024, 1024, 1024};
        for (int i = 0; i < 18; i++) { da.p[i] = srcs[i]; da.nw[i] = nele[i] < 4096 ? nele[i] : 4096; }
    }
    k_detect_all<<<18, 256, 0, stream>>>(da, flags);

    k_expand_mask<<<16, 256, 0, stream>>>(mask, flags + 1, maskb);
    k_convert_bf<<<32768, 256, 0, stream>>>(y, y_c, 8388608, flags + 0);

    TransArgs ta;
    {
        const void* s6[6] = {Wq, Wk, Wv, Wm, W1, W2};
        u16* d6[6] = {WqT, WkT, WvT, WmT, W1T, W2T};
        int R6[6] = {512, 512, 512, 1024, 1024, 2048};
        int C6[6] = {512, 512, 512, 1024, 4096, 512};
        int f6[6] = {6, 4, 2, 8, 10, 12};
        int ts[7] = {0, 256, 512, 768, 1792, 5888, 6912};
        for (int i = 0; i < 6; i++) { ta.src[i] = s6[i]; ta.dst[i] = d6[i]; ta.R[i] = R6[i]; ta.C[i] = C6[i]; ta.flagidx[i] = f6[i]; }
        for (int i = 0; i < 7; i++) ta.tstart[i] = ts[i];
    }
    k_transpose_all<<<6912, 256, 0, stream>>>(ta, flags);

    ConvArgs ca;
    {
        const void* s10[10] = {bq, bk, bv, bm, b1, b2, g1, be1, g2, be2};
        int f10[10] = {7, 5, 3, 9, 11, 13, 14, 15, 16, 17};
        int o10[10] = {0, 512, 1024, 1536, 2560, 6656, 7168, 8192, 9216, 10240};
        int n10[10] = {512, 512, 512, 1024, 4096, 512, 1024, 1024, 1024, 1024};
        for (int i = 0; i < 10; i++) { ca.src[i] = s10[i]; ca.flagidx[i] = f10[i]; ca.off[i] = o10[i]; ca.n[i] = n10[i]; }
    }
    k_convert_params<<<44, 256, 0, stream>>>(ca, flags, par);

    u16* qproj = slotA;
    u16* kproj = slotB;
    u16* vT    = slotC;
    u16* vproj = slotD;

    k_gemm_qkv<<<dim3(4, 64, 6), 256, 0, stream>>>(y_c, WqT, WkT, WvT, par, qproj, kproj, vproj);
    k_transpose_v<<<dim3(8, 8, 32), 256, 0, stream>>>(vproj, vT);

    u16* P = Pbig;
    k_attn_scores<<<dim3(4, 512), 256, 0, stream>>>(qproj, kproj, maskb, P);

    u16* attedpre = slotD;   // vproj dead
    k_gemm_ctx<<<dim3(2, 512), 256, 0, stream>>>(P, vT, attedpre);

    u16* mergeout = slotA;   // qproj dead
    k_gemm_std<false><<<dim3(8, 64), 256, 0, stream>>>(attedpre, 1024, WmT, 1024, p_bm, mergeout, 1024, 1024);

    u16* y1 = slotB;         // kproj dead
    k_ln<0><<<8192, 256, 0, stream>>>(y_c, mergeout, p_g1, p_be1, y1, nullptr);

    u16* h1 = Pbig;          // P dead after ctx
    k_gemm_std<true><<<dim3(32, 64), 256, 0, stream>>>(y1, 1024, W1T, 1024, p_b1, h1, 4096, 1024);

    u16* ffout = slotC;      // vT dead
    k_gemm_ffn2<<<dim3(8, 64), 256, 0, stream>>>(h1, W2T, p_b2, ffout);

    k_ln<1><<<8192, 256, 0, stream>>>(y1, ffout, p_g2, p_be2, d_out, flags + 0);
}